// Round 5
// baseline (521.723 us; speedup 1.0000x reference)
//
#include <hip/hip_runtime.h>
#include <cstddef>
#include <cstdint>

// Problem constants
#define DIMC 1024
#define HC   16
#define DHC  64
#define LC   32
#define WC   8
#define EC   4
#define SEQC 4096
#define BC   4
#define MTOT 16384    // B * SEQ

typedef __attribute__((ext_vector_type(8))) __bf16 bf16x8;
typedef __attribute__((ext_vector_type(4))) float f32x4;

__device__ inline unsigned short f2b(float f) {
  unsigned int u = __float_as_uint(f);
  u += 0x7fff + ((u >> 16) & 1);   // round-to-nearest-even
  return (unsigned short)(u >> 16);
}
__device__ inline float b2f(unsigned short u) {
  return __uint_as_float(((unsigned int)u) << 16);
}

// async global->LDS, 16B/lane; LDS dest = wave-uniform base + lane*16.
__device__ inline void gll16(const void* g, void* l) {
  __builtin_amdgcn_global_load_lds(
      (__attribute__((address_space(1))) void*)g,
      (__attribute__((address_space(3))) void*)l, 16, 0, 0);
}

// ---------------------------------------------------------------------------
// Row convert fp32 -> bf16 with (s,b,.)->(b,s,.) transpose folded in.
// ---------------------------------------------------------------------------
__global__ __launch_bounds__(256) void conv_rows(const float* __restrict__ src,
    unsigned short* __restrict__ dst) {
  int r = blockIdx.x;
  int sr = ((r & 4095) << 2) | (r >> 12);
  const float4* s = (const float4*)(src + (size_t)sr * 1024);
  ushort4* d = (ushort4*)(dst + (size_t)r * 1024);
  int t = threadIdx.x;
  float4 v = s[t];
  d[t] = make_ushort4(f2b(v.x), f2b(v.y), f2b(v.z), f2b(v.w));
}

// ---------------------------------------------------------------------------
// All weight transposes in one dispatch. z: 0=Wq 1=Wk 2=Wv 3=Wd 4=Wo.
// ---------------------------------------------------------------------------
__global__ __launch_bounds__(256) void conv_wT_all(
    const float* __restrict__ Wq, const float* __restrict__ Wk,
    const float* __restrict__ Wv, const float* __restrict__ Wd,
    const float* __restrict__ Wo, unsigned short* __restrict__ wAll,
    unsigned short* __restrict__ woT) {
  __shared__ float tile[32][33];
  int z = blockIdx.z;
  const float* W = (z == 0) ? Wq : (z == 1) ? Wk : (z == 2) ? Wv
                   : (z == 3) ? Wd : Wo;
  unsigned short* WT = (z == 4) ? woT : (wAll + (size_t)z * 1048576);
  int N = (z == 3) ? 512 : 1024;
  int n0 = blockIdx.x * 32, k0 = blockIdx.y * 32;
  if (n0 >= N) return;
  int t = threadIdx.x;
  int tr = t >> 5, tc = t & 31;
#pragma unroll
  for (int i = 0; i < 4; ++i)
    tile[tr + i * 8][tc] = W[(size_t)(k0 + tr + i * 8) * N + n0 + tc];
  __syncthreads();
#pragma unroll
  for (int i = 0; i < 4; ++i)
    WT[(size_t)(n0 + tr + i * 8) * 1024 + k0 + tc] = f2b(tile[tc][tr + i * 8]);
}

// ---------------------------------------------------------------------------
// 256x256 bf16 MFMA GEMM (R5): BK=32, 8 waves (512 thr), 64 KB LDS dbuf
// -> 2 blocks/CU co-residency. Counted-vmcnt depth-2 pipeline (vmcnt(4)),
// XOR-swizzled LDS (slot = q4 ^ ((m>>1)&3), <=2-way = free) via pre-swizzled
// global source for global_load_lds, setprio, XCD-chunked block swizzle.
// Epilogue C-stage chunked to 128 rows (67.6 KB declared dyn-LDS).
// mode 0: QKVD fused epilogue. mode 1: fp32 out + (b,s)->(s,b) remap.
// Pipeline per tile kt: compute buf[c] -> bar -> stage kt+2 into buf[c]
// -> vmcnt(4) (waits kt+1's 4 loads; kt+2's stay in flight) -> bar.
// ---------------------------------------------------------------------------
__global__ __launch_bounds__(512, 2) void gemm256(
    const unsigned short* __restrict__ A, const unsigned short* __restrict__ BT,
    const float* __restrict__ b0, const float* __restrict__ b1,
    const float* __restrict__ b2, const float* __restrict__ b3,
    unsigned short* __restrict__ o0, unsigned short* __restrict__ o1,
    unsigned short* __restrict__ o2, float* __restrict__ oy,
    float* __restrict__ outf, int mode) {
  extern __shared__ char smb[];
  unsigned short* smu = (unsigned short*)smb;
  int t = threadIdx.x;
  int w = t >> 6, lane = t & 63;
  int m = lane & 15, q4 = lane >> 4;
  int wr = (w >> 2) * 128, wc = (w & 3) * 64;
  int id = blockIdx.x;
  int xcd = id & 7, jj0 = id >> 3;
  int rowT = xcd * 8 + (jj0 & 7), colT = jj0 >> 3;
  int rowBase = rowT * 256, nBase = colT * 256;

  // staging: per tile 4 gll16/thread (A p0, A p1, B p0, B p1).
  // lane covers row = p*128 + (t>>2), granule (t&3); source granule
  // pre-swizzled by ((t>>3)&3) so LDS stays linear.
  int srow = t >> 2;                               // 0..127
  int gsw = ((t & 3) ^ ((t >> 3) & 3)) * 8;        // ushorts
  const unsigned short* gA0 = A + (size_t)(rowBase + srow) * 1024 + gsw;
  const unsigned short* gA1 = A + (size_t)(rowBase + 128 + srow) * 1024 + gsw;
  const unsigned short* gB0 = BT + (size_t)(nBase + srow) * 1024 + gsw;
  const unsigned short* gB1 = BT + (size_t)(nBase + 128 + srow) * 1024 + gsw;
  int ldsP0 = w * 1024;                            // bytes (pass 0)
  int ldsP1 = 8192 + w * 1024;                     // bytes (pass 1)
  // fragment read swizzle: slot = q4 ^ ((m>>1)&3) (ushort offset sx)
  int sx = (q4 ^ ((m >> 1) & 3)) * 8;
  f32x4 acc[8][4] = {};

#define STAGE5(kt_, c_)                                              \
  {                                                                  \
    int kc_ = (kt_) * 32;                                            \
    gll16(gA0 + kc_, smb + (c_)*16384 + ldsP0);                      \
    gll16(gA1 + kc_, smb + (c_)*16384 + ldsP1);                      \
    gll16(gB0 + kc_, smb + 32768 + (c_)*16384 + ldsP0);              \
    gll16(gB1 + kc_, smb + 32768 + (c_)*16384 + ldsP1);              \
  }

  // prologue: tiles 0 and 1; wait tile 0's 4 loads (tile 1 in flight)
  STAGE5(0, 0);
  STAGE5(1, 1);
  asm volatile("s_waitcnt vmcnt(4)" ::: "memory");
  __builtin_amdgcn_s_barrier();
  __builtin_amdgcn_sched_barrier(0);

  for (int kt = 0; kt < 32; ++kt) {
    int c = kt & 1;
    const unsigned short* Au = smu + c * 8192;
    const unsigned short* Bu = smu + 16384 + c * 8192;
    bf16x8 bf[4];
#pragma unroll
    for (int jj = 0; jj < 4; ++jj)
      bf[jj] = *(const bf16x8*)(Bu + (wc + jj * 16 + m) * 32 + sx);
#pragma unroll
    for (int ip = 0; ip < 4; ++ip) {
      bf16x8 af0 = *(const bf16x8*)(Au + (wr + (ip * 2) * 16 + m) * 32 + sx);
      bf16x8 af1 =
          *(const bf16x8*)(Au + (wr + (ip * 2 + 1) * 16 + m) * 32 + sx);
      __builtin_amdgcn_s_setprio(1);
#pragma unroll
      for (int jj = 0; jj < 4; ++jj)
        acc[ip * 2][jj] = __builtin_amdgcn_mfma_f32_16x16x32_bf16(
            af0, bf[jj], acc[ip * 2][jj], 0, 0, 0);
#pragma unroll
      for (int jj = 0; jj < 4; ++jj)
        acc[ip * 2 + 1][jj] = __builtin_amdgcn_mfma_f32_16x16x32_bf16(
            af1, bf[jj], acc[ip * 2 + 1][jj], 0, 0, 0);
      __builtin_amdgcn_s_setprio(0);
    }
    if (kt == 31) break;
    __builtin_amdgcn_s_barrier();     // all waves done reading buf[c]
    if (kt < 30) {
      STAGE5(kt + 2, c);
      asm volatile("s_waitcnt vmcnt(4)" ::: "memory");
    } else {
      asm volatile("s_waitcnt vmcnt(0)" ::: "memory");
    }
    __builtin_amdgcn_s_barrier();     // next-tile data landed for everyone
    __builtin_amdgcn_sched_barrier(0);
  }
  __syncthreads();

  // ---------------- epilogue ----------------
  int segBase = nBase + wc;
  if (mode == 1) {
#pragma unroll
    for (int jj = 0; jj < 4; ++jj) {
      float bvv = b0[segBase + jj * 16 + m];
#pragma unroll
      for (int i = 0; i < 8; ++i)
#pragma unroll
        for (int r = 0; r < 4; ++r) {
          int rr = rowBase + wr + i * 16 + q4 * 4 + r;
          int orow = ((rr & 4095) << 2) | (rr >> 12);
          outf[(size_t)orow * 1024 + segBase + jj * 16 + m] =
              acc[i][jj][r] + bvv;
        }
    }
    return;
  }
  int seg = segBase >> 10;    // uniform per block
  if (seg == 3) {             // head-score fp32 segment (N=512)
    int lc = segBase - 3072;
#pragma unroll
    for (int jj = 0; jj < 4; ++jj) {
      float bvv = b3[lc + jj * 16 + m];
#pragma unroll
      for (int i = 0; i < 8; ++i)
#pragma unroll
        for (int r = 0; r < 4; ++r)
          oy[(size_t)(rowBase + wr + i * 16 + q4 * 4 + r) * 512 + lc +
             jj * 16 + m] = acc[i][jj][r] + bvv;
    }
    return;
  }
  const float* bp = (seg == 0) ? b0 : (seg == 1) ? b1 : b2;
  unsigned short* ob = (seg == 0) ? o0 : (seg == 1) ? o1 : o2;
  float scl = (seg == 0) ? 0.125f : 1.0f;
  int lc0 = nBase & 1023;
  // chunked C-stage: 128 rows at a time in LDS [128][264], then 16B stores
#pragma unroll
  for (int h = 0; h < 2; ++h) {
    if ((w >> 2) == h) {
#pragma unroll
      for (int jj = 0; jj < 4; ++jj) {
        float bvv = bp[lc0 + wc + jj * 16 + m];
#pragma unroll
        for (int i = 0; i < 8; ++i)
#pragma unroll
          for (int r = 0; r < 4; ++r)
            smu[(i * 16 + q4 * 4 + r) * 264 + wc + jj * 16 + m] =
                f2b((acc[i][jj][r] + bvv) * scl);
      }
    }
    __syncthreads();
#pragma unroll
    for (int rd = 0; rd < 8; ++rd) {
      int idx = rd * 512 + t;
      int row = idx >> 5, cs = (idx & 31) * 8;
      uint4 v = *(const uint4*)(smu + row * 264 + cs);
      *(uint4*)(ob + (size_t)(rowBase + h * 128 + row) * 1024 + lc0 + cs) = v;
    }
    __syncthreads();
  }
}

// ---------------------------------------------------------------------------
// In-place row LayerNorm on bf16 buffer (1024 cols, fp32 math).
// ---------------------------------------------------------------------------
__global__ __launch_bounds__(256) void ln_bf(unsigned short* __restrict__ buf,
    const float* __restrict__ g, const float* __restrict__ b) {
  int row = blockIdx.x;
  unsigned short* p = buf + (size_t)row * 1024;
  int tid = threadIdx.x;
  ushort4 u4 = ((const ushort4*)p)[tid];
  float x0 = b2f(u4.x), x1 = b2f(u4.y), x2 = b2f(u4.z), x3 = b2f(u4.w);
  float s = x0 + x1 + x2 + x3;
  float ss = x0 * x0 + x1 * x1 + x2 * x2 + x3 * x3;
#pragma unroll
  for (int off = 32; off > 0; off >>= 1) {
    s += __shfl_down(s, off);
    ss += __shfl_down(ss, off);
  }
  __shared__ float sred[8], ssred[8];
  int wave = tid >> 6, lane = tid & 63;
  if (lane == 0) { sred[wave] = s; ssred[wave] = ss; }
  __syncthreads();
  if (tid == 0) {
    float S = 0, SS = 0;
    for (int w = 0; w < 4; ++w) { S += sred[w]; SS += ssred[w]; }
    float m = S * (1.0f / 1024.0f);
    float v = SS * (1.0f / 1024.0f) - m * m;
    sred[0] = m;
    ssred[0] = rsqrtf(v + 1e-5f);
  }
  __syncthreads();
  float m = sred[0], rinv = ssred[0];
  float4 gg = ((const float4*)g)[tid];
  float4 bb = ((const float4*)b)[tid];
  ushort4 y;
  y.x = f2b((x0 - m) * rinv * gg.x + bb.x);
  y.y = f2b((x1 - m) * rinv * gg.y + bb.y);
  y.z = f2b((x2 - m) * rinv * gg.z + bb.z);
  y.w = f2b((x3 - m) * rinv * gg.w + bb.w);
  ((ushort4*)p)[tid] = y;
}

// ---------------------------------------------------------------------------
// Column softmax stats, phase A: per-chunk partials.
// ---------------------------------------------------------------------------
__global__ __launch_bounds__(256) void col_part(const float* __restrict__ yd,
    float* __restrict__ pm, float* __restrict__ ps) {
  int cg = blockIdx.x, b = blockIdx.y, sc = blockIdx.z;
  int t = threadIdx.x;
  int lane = t & 63, grp = t >> 6;
  const float* base = yd + (size_t)b * 4096 * 512 + (size_t)(sc * 256) * 512 +
                      cg * 64 + lane;
  float m = -1e30f, s = 0.f;
  for (int r = grp; r < 256; r += 4) {
    float x = base[(size_t)r * 512];
    float mn = fmaxf(m, x);
    s = s * expf(m - mn) + expf(x - mn);
    m = mn;
  }
  __shared__ float mS[4][64], sS[4][64];
  mS[grp][lane] = m;
  sS[grp][lane] = s;
  __syncthreads();
  if (grp == 0) {
    float M = mS[0][lane], S = sS[0][lane];
#pragma unroll
    for (int k = 1; k < 4; ++k) {
      float m2 = mS[k][lane], s2 = sS[k][lane];
      float Mn = fmaxf(M, m2);
      S = S * expf(M - Mn) + s2 * expf(m2 - Mn);
      M = Mn;
    }
    int col = cg * 64 + lane;
    pm[((size_t)(b * 512 + col)) * 16 + sc] = M;
    ps[((size_t)(b * 512 + col)) * 16 + sc] = S;
  }
}

// ---------------------------------------------------------------------------
// Column softmax stats, phase B: merge 16 partials per column.
// ---------------------------------------------------------------------------
__global__ __launch_bounds__(256) void col_combine(const float* __restrict__ pm,
    const float* __restrict__ ps, float* __restrict__ stats) {
  int idx = blockIdx.x * 256 + threadIdx.x;  // (b*512+col)
  float M = -1e30f, S = 0.f;
#pragma unroll
  for (int sc = 0; sc < 16; ++sc) {
    float m2 = pm[(size_t)idx * 16 + sc], s2 = ps[(size_t)idx * 16 + sc];
    float Mn = fmaxf(M, m2);
    S = S * expf(M - Mn) + s2 * expf(m2 - Mn);
    M = Mn;
  }
  stats[(size_t)idx * 2] = M;
  stats[(size_t)idx * 2 + 1] = 1.0f / S;
}

// ---------------------------------------------------------------------------
// Landmark compression partials; K/V bf16. (R1 LDS-staged outer product.)
// ---------------------------------------------------------------------------
#define NCHUNK 32
#define SCH    128
__global__ __launch_bounds__(256) void compress(const float* __restrict__ yd,
    const float* __restrict__ stats, const unsigned short* __restrict__ kbuf,
    const unsigned short* __restrict__ vbuf, float* __restrict__ kcp,
    float* __restrict__ vcp) {
  int c = blockIdx.x, h = blockIdx.y, b = blockIdx.z;
  int tid = threadIdx.x;
  int dq = tid & 15;     // output d = dq*4 .. dq*4+3
  int lp = tid >> 4;     // output l = lp*2, lp*2+1
  __shared__ float mxS[32], isS[32];
  __shared__ float pS[16][32];
  __shared__ float KfS[16][64];
  __shared__ float VfS[16][64];
  if (tid < 32) {
    mxS[tid] = stats[(size_t)(b * 512 + h * 32 + tid) * 2];
    isS[tid] = stats[(size_t)(b * 512 + h * 32 + tid) * 2 + 1];
  }
  __syncthreads();
  f32x4 aK0 = {}, aK1 = {}, aV0 = {}, aV1 = {};
  int s0 = c * SCH;
  for (int sc = 0; sc < SCH; sc += 16) {
    int bs = b * 4096 + s0 + sc;
    {
      int sl = tid >> 4;
      int l2 = (tid & 15) * 2;
      const float2 yv =
          *(const float2*)(yd + ((size_t)(bs + sl)) * 512 + h * 32 + l2);
      pS[sl][l2] = expf(yv.x - mxS[l2]) * isS[l2];
      pS[sl][l2 + 1] = expf(yv.y - mxS[l2 + 1]) * isS[l2 + 1];
      size_t roff = ((size_t)(bs + sl)) * 1024 + h * 64 + (tid & 15) * 4;
      ushort4 ku = *(const ushort4*)(kbuf + roff);
      ushort4 vu = *(const ushort4*)(vbuf + roff);
      f32x4 kf, vf;
      kf[0] = b2f(ku.x); kf[1] = b2f(ku.y); kf[2] = b2f(ku.z); kf[3] = b2f(ku.w);
      vf[0] = b2f(vu.x); vf[1] = b2f(vu.y); vf[2] = b2f(vu.z); vf[3] = b2f(vu.w);
      *(f32x4*)&KfS[sl][(tid & 15) * 4] = kf;
      *(f32x4*)&VfS[sl][(tid & 15) * 4] = vf;
    }
    __syncthreads();
#pragma unroll
    for (int sl = 0; sl < 16; ++sl) {
      float p0 = pS[sl][lp * 2];
      float p1 = pS[sl][lp * 2 + 1];
      const f32x4 kk = *(const f32x4*)&KfS[sl][dq * 4];
      const f32x4 vv = *(const f32x4*)&VfS[sl][dq * 4];
#pragma unroll
      for (int q = 0; q < 4; ++q) {
        aK0[q] += p0 * kk[q];
        aK1[q] += p1 * kk[q];
        aV0[q] += p0 * vv[q];
        aV1[q] += p1 * vv[q];
      }
    }
    __syncthreads();
  }
  size_t o0 = ((((size_t)c * 4 + b) * 16 + h) * 32 + (lp * 2)) * 64 + dq * 4;
  *(f32x4*)&kcp[o0] = aK0;
  *(f32x4*)&kcp[o0 + 64] = aK1;
  *(f32x4*)&vcp[o0] = aV0;
  *(f32x4*)&vcp[o0 + 64] = aV1;
}

// ---------------------------------------------------------------------------
// Reduce compression partials (32 chunks) + LayerNorm (fp32).
// ---------------------------------------------------------------------------
__global__ __launch_bounds__(256) void ln_compress(const float* __restrict__ kcp,
    const float* __restrict__ vcp, const float* __restrict__ g_s,
    const float* __restrict__ b_s, float* __restrict__ kc_ln,
    float* __restrict__ vc_ln) {
  int row = blockIdx.x;            // b*32 + l
  int b = row >> 5, l = row & 31;
  const float* part = blockIdx.y ? vcp : kcp;
  float* outp = blockIdx.y ? vc_ln : kc_ln;
  int tid = threadIdx.x;
  int h = tid >> 4, d4 = (tid & 15) * 4;
  size_t base = (((size_t)b * 16 + h) * 32 + l) * 64 + d4;
  f32x4 x = {};
#pragma unroll
  for (int cch = 0; cch < NCHUNK; ++cch) {
    const f32x4 v = *(const f32x4*)&part[base + (size_t)cch * 131072];
#pragma unroll
    for (int q = 0; q < 4; ++q) x[q] += v[q];
  }
  float lsum = x[0] + x[1] + x[2] + x[3];
  float lss = x[0] * x[0] + x[1] * x[1] + x[2] * x[2] + x[3] * x[3];
#pragma unroll
  for (int off = 32; off > 0; off >>= 1) {
    lsum += __shfl_down(lsum, off);
    lss += __shfl_down(lss, off);
  }
  __shared__ float red[8], red2[8];
  int wave = tid >> 6, lane = tid & 63;
  if (lane == 0) { red[wave] = lsum; red2[wave] = lss; }
  __syncthreads();
  if (tid == 0) {
    float S = 0, SS = 0;
    for (int w = 0; w < 4; ++w) { S += red[w]; SS += red2[w]; }
    float m = S * (1.0f / 1024.0f);
    float v = SS * (1.0f / 1024.0f) - m * m;
    red[0] = m;
    red2[0] = rsqrtf(v + 1e-5f);
  }
  __syncthreads();
  float m = red[0], rinv = red2[0];
  int j = tid * 4;  // == h*64 + d4
  const float4 gg = *(const float4*)(g_s + j);
  const float4 bb = *(const float4*)(b_s + j);
  float4 yo;
  yo.x = (x[0] - m) * rinv * gg.x + bb.x;
  yo.y = (x[1] - m) * rinv * gg.y + bb.y;
  yo.z = (x[2] - m) * rinv * gg.z + bb.z;
  yo.w = (x[3] - m) * rinv * gg.w + bb.w;
  *(float4*)(outp + (size_t)row * 1024 + j) = yo;
}

// ---------------------------------------------------------------------------
// Fused attention (R2: MFMA rewrite).
// ---------------------------------------------------------------------------
__global__ __launch_bounds__(256) void attention(unsigned short* __restrict__ qc,
    const unsigned short* __restrict__ kbuf,
    const unsigned short* __restrict__ vbuf,
    const float* __restrict__ kc_ln, const float* __restrict__ vc_ln) {
  int qt = blockIdx.x, h = blockIdx.y, b = blockIdx.z;
  int t = threadIdx.x;
  int l = t & 63, w = t >> 6;
  int lr16 = l & 15, q4 = l >> 4;
  int s0 = qt * 64, hoff = h * 64;

  __shared__ unsigned short regionA[12672];  // 25344 B
  __shared__ unsigned short Vt[64 * 128];    // 16384 B, XOR-swz k^((d&31)<<2)
  unsigned short* Qs = regionA;              // [64][72]
  unsigned short* Ks = regionA + 64 * 72;    // [112][72] (rows>=104 unused)
  unsigned short* Ps = regionA;              // alias: [64][128] swz blk^(q&7)
  unsigned short* Cs = regionA + 64 * 128;   // alias: [64][68]

  // ---- stage Q (64x64 bf16) ----
#pragma unroll
  for (int it = 0; it < 2; ++it) {
    int sid = it * 256 + t;
    int row = sid >> 3, seg = sid & 7;
    uint4 v = *(const uint4*)(qc + ((size_t)(b * 4096 + s0 + row)) * 1024 +
                              hoff + seg * 8);
    *(uint4*)(Qs + row * 72 + seg * 8) = v;
  }
  // ---- stage Kc (32x64 fp32 -> bf16), rows 0..31 of Ks ----
#pragma unroll
  for (int it = 0; it < 2; ++it) {
    int sid = it * 256 + t;
    int row = sid >> 4, s4 = sid & 15;
    float4 v = *(const float4*)(kc_ln + ((size_t)(b * 32 + row)) * 1024 +
                                hoff + s4 * 4);
    ushort4 u = make_ushort4(f2b(v.x), f2b(v.y), f2b(v.z), f2b(v.w));
    *(ushort4*)(Ks + row * 72 + s4 * 4) = u;
  }
  // ---- stage Kw (72 window rows), rows 32..103 of Ks ----
#pragma unroll
  for (int it = 0; it < 3; ++it) {
    int sid = it * 256 + t;
    if (sid < 576) {
      int r = sid >> 3, seg = sid & 7;
      int pos = s0 - 4 + r;
      uint4 v = {0, 0, 0, 0};
      if (pos >= 0 && pos < 4096)
        v = *(const uint4*)(kbuf + ((size_t)(b * 4096 + pos)) * 1024 + hoff +
                            seg * 8);
      *(uint4*)(Ks + (32 + r) * 72 + seg * 8) = v;
    }
  }
  // ---- stage Vt (transposed, 64 d x 128 k-slots; slots>=104 zero) ----
#pragma unroll
  for (int it = 0; it < 8; ++it) {
    int d = t & 63;
    int k0 = (t >> 6) * 4 + it * 16;
    unsigned short vv[4];
#pragma unroll
    for (int i = 0; i < 4; ++i) {
      int kk = k0 + i;
      unsigned short x = 0;
      if (kk < 32) {
        x = f2b(vc_ln[((size_t)(b * 32 + kk)) * 1024 + hoff + d]);
      } else if (kk < 104) {
        int pos = s0 - 4 + (kk - 32);
        if (pos >= 0 && pos < 4096)
          x = vbuf[((size_t)(b * 4096 + pos)) * 1024 + hoff + d];
      }
      vv[i] = x;
    }
    *(ushort4*)(Vt + d * 128 + (k0 ^ ((d & 31) << 2))) = *(ushort4*)vv;
  }
  __syncthreads();

  // ---- QK^T: wave w handles queries mbase..mbase+15 ----
  int mbase = w * 16;
  bf16x8 aq[2];
#pragma unroll
  for (int ks = 0; ks < 2; ++ks)
    aq[ks] = *(const bf16x8*)(Qs + (mbase + lr16) * 72 + ks * 32 + q4 * 8);
  f32x4 S[7];
#pragma unroll
  for (int nb = 0; nb < 7; ++nb) {
    f32x4 acc = {};
#pragma unroll
    for (int ks = 0; ks < 2; ++ks) {
      bf16x8 bk =
          *(const bf16x8*)(Ks + (nb * 16 + lr16) * 72 + ks * 32 + q4 * 8);
      acc = __builtin_amdgcn_mfma_f32_16x16x32_bf16(aq[ks], bk, acc, 0, 0, 0);
    }
    S[nb] = acc;
  }

  // ---- mask + softmax in-register ----
  float ex[7][4];
#pragma unroll
  for (int r = 0; r < 4; ++r) {
    int qrow = mbase + q4 * 4 + r;        // block-local query 0..63
    int g8 = (qrow >> 3) * 8;
    float m = -1e30f;
#pragma unroll
    for (int nb = 0; nb < 7; ++nb) {
      int col = nb * 16 + lr16;
      float v = S[nb][r];
      if (col >= 32) {
        int rw = col - 32;
        int pos = s0 - 4 + rw;
        bool ok = (rw >= g8) && (rw < g8 + 16) && (pos >= 0) && (pos < 4096);
        if (!ok) v = -INFINITY;
      }
      ex[nb][r] = v;
      m = fmaxf(m, v);
    }
    m = fmaxf(m, __shfl_xor(m, 1));
    m = fmaxf(m, __shfl_xor(m, 2));
    m = fmaxf(m, __shfl_xor(m, 4));
    m = fmaxf(m, __shfl_xor(m, 8));
    float s = 0.f;
#pragma unroll
    for (int nb = 0; nb < 7; ++nb) {
      float e = expf(ex[nb][r] - m);
      ex[nb][r] = e;
      s += e;
    }
    s += __shfl_xor(s, 1);
    s += __shfl_xor(s, 2);
    s += __shfl_xor(s, 4);
    s += __shfl_xor(s, 8);
    float inv = 1.0f / s;
#pragma unroll
    for (int nb = 0; nb < 7; ++nb) ex[nb][r] *= inv;
  }
  __syncthreads();   // all QK reads of Qs/Ks done; regionA now P/C

  // zero P pad cols 112..127 (swizzled blocks 14,15 per row)
  if (t < 128) {
    int q = t >> 1, blk = 14 + (t & 1);
    uint4 z = {0, 0, 0, 0};
    *(uint4*)(Ps + q * 128 + ((blk ^ (q & 7)) << 3)) = z;
  }
  // write P bf16 (swizzled 16B blocks)
#pragma unroll
  for (int r = 0; r < 4; ++r) {
    int q = mbase + q4 * 4 + r;
#pragma unroll
    for (int nb = 0; nb < 7; ++nb) {
      int col = nb * 16 + lr16;
      int blk = col >> 3;
      Ps[q * 128 + ((blk ^ (q & 7)) << 3) + (col & 7)] = f2b(ex[nb][r]);
    }
  }
  __syncthreads();

  // ---- PV: C[q][d] = sum_k P[q][k] * V[k][d] ----
  bf16x8 pa[4];
#pragma unroll
  for (int ks = 0; ks < 4; ++ks) {
    int q = mbase + lr16;
    int blk = ks * 4 + q4;
    pa[ks] = *(const bf16x8*)(Ps + q * 128 + ((blk ^ (q & 7)) << 3));
  }
#pragma unroll
  for (int nb = 0; nb < 4; ++nb) {
    f32x4 acc = {};
    int d = nb * 16 + lr16;
#pragma unroll
    for (int ks = 0; ks < 4; ++ks) {
      unsigned short vv[8];
#pragma unroll
      for (int jh = 0; jh < 2; ++jh) {
        int k4 = ks * 32 + q4 * 8 + jh * 4;
        *(ushort4*)(vv + jh * 4) =
            *(const ushort4*)(Vt + d * 128 + (k4 ^ ((d & 31) << 2)));
      }
      acc = __builtin_amdgcn_mfma_f32_16x16x32_bf16(pa[ks], *(const bf16x8*)vv,
                                                    acc, 0, 0, 0);
    }
#pragma unroll
    for (int r = 0; r < 4; ++r) {
      int row = mbase + q4 * 4 + r;
      Cs[row * 68 + d] = f2b(acc[r]);
    }
  }
  __syncthreads();

  // ---- store C (coalesced 16B) ----
#pragma unroll
  for (int it = 0; it < 2; ++it) {
    int sid = it * 256 + t;
    int row = sid >> 3, seg = sid & 7;
    ushort4 a0 = *(const ushort4*)(Cs + row * 68 + seg * 8);
    ushort4 a1 = *(const ushort4*)(Cs + row * 68 + seg * 8 + 4);
    unsigned short u[8];
    *(ushort4*)u = a0;
    *(ushort4*)(u + 4) = a1;
    *(uint4*)(qc + ((size_t)(b * 4096 + s0 + row)) * 1024 + hoff + seg * 8) =
        *(uint4*)u;
  }
}

// ---------------------------------------------------------------------------
extern "C" void kernel_launch(void* const* d_in, const int* in_sizes, int n_in,
                              void* d_out, int out_size, void* d_ws,
                              size_t ws_size, hipStream_t stream) {
  const float* query = (const float*)d_in[0];
  const float* Wq = (const float*)d_in[1];
  const float* bq = (const float*)d_in[2];
  const float* Wk = (const float*)d_in[3];
  const float* bk = (const float*)d_in[4];
  const float* Wv = (const float*)d_in[5];
  const float* bv = (const float*)d_in[6];
  const float* Wo = (const float*)d_in[7];
  const float* bo = (const float*)d_in[8];
  const float* g_l = (const float*)d_in[9];
  const float* b_l = (const float*)d_in[10];
  const float* g_s = (const float*)d_in[11];
  const float* b_s = (const float*)d_in[12];
  const float* Wd = (const float*)d_in[13];
  const float* bd = (const float*)d_in[14];
  float* out = (float*)d_out;

  // allow >64KB dynamic LDS for gemm256 (once per process)
  static bool attr_set = []() {
    hipFuncSetAttribute((const void*)gemm256,
                        hipFuncAttributeMaxDynamicSharedMemorySize, 135168);
    return true;
  }();
  (void)attr_set;

  // Workspace layout (~205 MB)
  unsigned short* qb = (unsigned short*)d_ws;  // 16,777,216 bf16 (Q, then C)
  unsigned short* kb = qb + 16777216;          // 16,777,216 bf16
  unsigned short* vb = kb + 16777216;          // 16,777,216 bf16
  unsigned short* xb = vb + 16777216;          // 16,777,216 bf16 (X)
  float* yd = (float*)(xb + 16777216);         // 8,388,608 fp32
  float* stats = yd + 8388608;                 // 4,096
  float* col_pm = stats + 4096;                // 32,768
  float* col_ps = col_pm + 32768;              // 32,768
  float* kc_part = col_ps + 32768;             // 4,194,304 (32 chunks)
  float* vc_part = kc_part + 4194304;          // 4,194,304
  float* kc_ln = vc_part + 4194304;            // 131,072
  float* vc_ln = kc_ln + 131072;               // 131,072
  // wAll: concatenated [WqT|WkT|WvT|WdT] rows (1024+1024+1024+512 = 3584)
  unsigned short* wAll = (unsigned short*)(vc_ln + 131072);  // 3,670,016
  unsigned short* woT = wAll + 3670016;        // 1,048,576

  dim3 blk(256);
  // bf16 conversions
  conv_rows<<<16384, blk, 0, stream>>>(query, xb);
  conv_wT_all<<<dim3(32, 32, 5), blk, 0, stream>>>(Wq, Wk, Wv, Wd, Wo,
                                                   wAll, woT);
  // Fused QKVD projections: 256^2 tiles, BK=32, 2 blocks/CU
  gemm256<<<896, dim3(512), 67584, stream>>>(xb, wAll, bq, bk, bv, bd,
                                             qb, kb, vb, yd, nullptr, 0);
  // LN K and V in one dispatch (kb,vb contiguous)
  ln_bf<<<32768, blk, 0, stream>>>(kb, g_l, b_l);
  // head-score softmax stats (two-phase, 512-block parallel)
  col_part<<<dim3(8, 4, 16), blk, 0, stream>>>(yd, col_pm, col_ps);
  col_combine<<<8, blk, 0, stream>>>(col_pm, col_ps, stats);
  // landmark compression + LN
  compress<<<dim3(NCHUNK, 16, 4), blk, 0, stream>>>(yd, stats, kb, vb,
                                                    kc_part, vc_part);
  ln_compress<<<dim3(128, 2), blk, 0, stream>>>(kc_part, vc_part, g_s, b_s,
                                                kc_ln, vc_ln);
  // fused attention (bf16 C overwrites qb)
  attention<<<dim3(64, 16, 4), blk, 0, stream>>>(qb, kb, vb, kc_ln, vc_ln);
  // output projection (+ (b,s)->(s,b) remap), reads bf16 C directly
  gemm256<<<256, dim3(512), 67584, stream>>>(qb, woT, bo, nullptr, nullptr,
                                             nullptr, nullptr, nullptr,
                                             nullptr, nullptr, out, 1);
}

// Round 6
// 504.993 us; speedup vs baseline: 1.0331x; 1.0331x over previous
//
#include <hip/hip_runtime.h>
#include <cstddef>
#include <cstdint>

// Problem constants
#define DIMC 1024
#define HC   16
#define DHC  64
#define LC   32
#define WC   8
#define EC   4
#define SEQC 4096
#define BC   4
#define MTOT 16384    // B * SEQ

typedef __attribute__((ext_vector_type(8))) __bf16 bf16x8;
typedef __attribute__((ext_vector_type(4))) float f32x4;

__device__ inline unsigned short f2b(float f) {
  unsigned int u = __float_as_uint(f);
  u += 0x7fff + ((u >> 16) & 1);   // round-to-nearest-even
  return (unsigned short)(u >> 16);
}
__device__ inline float b2f(unsigned short u) {
  return __uint_as_float(((unsigned int)u) << 16);
}

// async global->LDS, 16B/lane; LDS dest = wave-uniform base + lane*16.
__device__ inline void gll16(const void* g, void* l) {
  __builtin_amdgcn_global_load_lds(
      (__attribute__((address_space(1))) void*)g,
      (__attribute__((address_space(3))) void*)l, 16, 0, 0);
}

// ---------------------------------------------------------------------------
// Row convert fp32 -> bf16 with (s,b,.)->(b,s,.) transpose folded in.
// ---------------------------------------------------------------------------
__global__ __launch_bounds__(256) void conv_rows(const float* __restrict__ src,
    unsigned short* __restrict__ dst) {
  int r = blockIdx.x;
  int sr = ((r & 4095) << 2) | (r >> 12);
  const float4* s = (const float4*)(src + (size_t)sr * 1024);
  ushort4* d = (ushort4*)(dst + (size_t)r * 1024);
  int t = threadIdx.x;
  float4 v = s[t];
  d[t] = make_ushort4(f2b(v.x), f2b(v.y), f2b(v.z), f2b(v.w));
}

// ---------------------------------------------------------------------------
// All weight transposes in one dispatch. z: 0=Wq 1=Wk 2=Wv 3=Wd 4=Wo.
// ---------------------------------------------------------------------------
__global__ __launch_bounds__(256) void conv_wT_all(
    const float* __restrict__ Wq, const float* __restrict__ Wk,
    const float* __restrict__ Wv, const float* __restrict__ Wd,
    const float* __restrict__ Wo, unsigned short* __restrict__ wAll,
    unsigned short* __restrict__ woT) {
  __shared__ float tile[32][33];
  int z = blockIdx.z;
  const float* W = (z == 0) ? Wq : (z == 1) ? Wk : (z == 2) ? Wv
                   : (z == 3) ? Wd : Wo;
  unsigned short* WT = (z == 4) ? woT : (wAll + (size_t)z * 1048576);
  int N = (z == 3) ? 512 : 1024;
  int n0 = blockIdx.x * 32, k0 = blockIdx.y * 32;
  if (n0 >= N) return;
  int t = threadIdx.x;
  int tr = t >> 5, tc = t & 31;
#pragma unroll
  for (int i = 0; i < 4; ++i)
    tile[tr + i * 8][tc] = W[(size_t)(k0 + tr + i * 8) * N + n0 + tc];
  __syncthreads();
#pragma unroll
  for (int i = 0; i < 4; ++i)
    WT[(size_t)(n0 + tr + i * 8) * 1024 + k0 + tc] = f2b(tile[tc][tr + i * 8]);
}

// ---------------------------------------------------------------------------
// 256x256 bf16 MFMA GEMM (R6): BK=32, 8 waves (512 thr), FOUR 32 KB LDS
// buffers (128 KB), depth-3 prefetch with counted vmcnt(8), stage issued
// BEFORE compute (loads overlap MFMA), ONE barrier per K-tile.
// XOR-swizzled LDS via pre-swizzled global source (bank-conflict-free,
// measured 0), setprio around MFMA, XCD-chunked block swizzle.
// mode 0: QKVD fused epilogue. mode 1: fp32 out + (b,s)->(s,b) remap.
// Race-freedom: STAGE(kt+3 -> buf[(kt+3)&3]); that buffer was last read at
// iteration kt-1 ((kt+3)%4 == (kt-1)%4) whose ds_reads completed (lgkmcnt
// before MFMA) before its end-of-iteration barrier. vmcnt(8) waits the 4
// oldest outstanding loads = tile kt+1's (wave-uniform 4 loads/tile).
// ---------------------------------------------------------------------------
__global__ __launch_bounds__(512, 2) void gemm256(
    const unsigned short* __restrict__ A, const unsigned short* __restrict__ BT,
    const float* __restrict__ b0, const float* __restrict__ b1,
    const float* __restrict__ b2, const float* __restrict__ b3,
    unsigned short* __restrict__ o0, unsigned short* __restrict__ o1,
    unsigned short* __restrict__ o2, float* __restrict__ oy,
    float* __restrict__ outf, int mode) {
  extern __shared__ char smb[];
  unsigned short* smu = (unsigned short*)smb;
  int t = threadIdx.x;
  int w = t >> 6, lane = t & 63;
  int m = lane & 15, q4 = lane >> 4;
  int wr = (w >> 2) * 128, wc = (w & 3) * 64;
  int id = blockIdx.x;
  int xcd = id & 7, jj0 = id >> 3;
  int rowT = xcd * 8 + (jj0 & 7), colT = jj0 >> 3;
  int rowBase = rowT * 256, nBase = colT * 256;

  // staging: per tile 4 gll16/thread (A p0, A p1, B p0, B p1).
  // lane covers row = p*128 + (t>>2), granule (t&3); source granule
  // pre-swizzled by ((t>>3)&3) so LDS stays linear.
  int srow = t >> 2;                               // 0..127
  int gsw = ((t & 3) ^ ((t >> 3) & 3)) * 8;        // ushorts
  const unsigned short* gA0 = A + (size_t)(rowBase + srow) * 1024 + gsw;
  const unsigned short* gA1 = A + (size_t)(rowBase + 128 + srow) * 1024 + gsw;
  const unsigned short* gB0 = BT + (size_t)(nBase + srow) * 1024 + gsw;
  const unsigned short* gB1 = BT + (size_t)(nBase + 128 + srow) * 1024 + gsw;
  int ldsP0 = w * 1024;                            // bytes (pass 0)
  int ldsP1 = 8192 + w * 1024;                     // bytes (pass 1)
  // fragment read swizzle: slot = q4 ^ ((m>>1)&3) (ushort offset sx)
  int sx = (q4 ^ ((m >> 1) & 3)) * 8;
  f32x4 acc[8][4] = {};

  // buffer bf layout: buffer c at byte c*32768; A = first 16 KB, B = next.
#define STAGE6(kt_, c_)                                              \
  {                                                                  \
    int kc_ = (kt_) * 32;                                            \
    gll16(gA0 + kc_, smb + (c_) * 32768 + ldsP0);                    \
    gll16(gA1 + kc_, smb + (c_) * 32768 + ldsP1);                    \
    gll16(gB0 + kc_, smb + (c_) * 32768 + 16384 + ldsP0);            \
    gll16(gB1 + kc_, smb + (c_) * 32768 + 16384 + ldsP1);            \
  }

  // prologue: tiles 0,1,2 into buffers 0,1,2 (12 loads); wait tile 0.
  STAGE6(0, 0);
  STAGE6(1, 1);
  STAGE6(2, 2);
  asm volatile("s_waitcnt vmcnt(8)" ::: "memory");
  __builtin_amdgcn_s_barrier();
  __builtin_amdgcn_sched_barrier(0);

  for (int kt = 0; kt < 32; ++kt) {
    int c = kt & 3;
    // issue next prefetch FIRST so loads overlap this tile's MFMA
    if (kt < 29) STAGE6(kt + 3, (kt + 3) & 3);
    const unsigned short* Au = smu + c * 16384;
    const unsigned short* Bu = smu + c * 16384 + 8192;
    bf16x8 bf[4];
#pragma unroll
    for (int jj = 0; jj < 4; ++jj)
      bf[jj] = *(const bf16x8*)(Bu + (wc + jj * 16 + m) * 32 + sx);
#pragma unroll
    for (int ip = 0; ip < 4; ++ip) {
      bf16x8 af0 = *(const bf16x8*)(Au + (wr + (ip * 2) * 16 + m) * 32 + sx);
      bf16x8 af1 =
          *(const bf16x8*)(Au + (wr + (ip * 2 + 1) * 16 + m) * 32 + sx);
      __builtin_amdgcn_s_setprio(1);
#pragma unroll
      for (int jj = 0; jj < 4; ++jj)
        acc[ip * 2][jj] = __builtin_amdgcn_mfma_f32_16x16x32_bf16(
            af0, bf[jj], acc[ip * 2][jj], 0, 0, 0);
#pragma unroll
      for (int jj = 0; jj < 4; ++jj)
        acc[ip * 2 + 1][jj] = __builtin_amdgcn_mfma_f32_16x16x32_bf16(
            af1, bf[jj], acc[ip * 2 + 1][jj], 0, 0, 0);
      __builtin_amdgcn_s_setprio(0);
    }
    if (kt == 31) break;
    // counted drain: wait only tile kt+1's loads; deeper prefetch stays out
    if (kt < 29) {
      asm volatile("s_waitcnt vmcnt(8)" ::: "memory");
    } else if (kt == 29) {
      asm volatile("s_waitcnt vmcnt(4)" ::: "memory");
    } else {
      asm volatile("s_waitcnt vmcnt(0)" ::: "memory");
    }
    __builtin_amdgcn_s_barrier();
    __builtin_amdgcn_sched_barrier(0);
  }
  __syncthreads();

  // ---------------- epilogue ----------------
  int segBase = nBase + wc;
  if (mode == 1) {
#pragma unroll
    for (int jj = 0; jj < 4; ++jj) {
      float bvv = b0[segBase + jj * 16 + m];
#pragma unroll
      for (int i = 0; i < 8; ++i)
#pragma unroll
        for (int r = 0; r < 4; ++r) {
          int rr = rowBase + wr + i * 16 + q4 * 4 + r;
          int orow = ((rr & 4095) << 2) | (rr >> 12);
          outf[(size_t)orow * 1024 + segBase + jj * 16 + m] =
              acc[i][jj][r] + bvv;
        }
    }
    return;
  }
  int seg = segBase >> 10;    // uniform per block
  if (seg == 3) {             // head-score fp32 segment (N=512)
    int lc = segBase - 3072;
#pragma unroll
    for (int jj = 0; jj < 4; ++jj) {
      float bvv = b3[lc + jj * 16 + m];
#pragma unroll
      for (int i = 0; i < 8; ++i)
#pragma unroll
        for (int r = 0; r < 4; ++r)
          oy[(size_t)(rowBase + wr + i * 16 + q4 * 4 + r) * 512 + lc +
             jj * 16 + m] = acc[i][jj][r] + bvv;
    }
    return;
  }
  const float* bp = (seg == 0) ? b0 : (seg == 1) ? b1 : b2;
  unsigned short* ob = (seg == 0) ? o0 : (seg == 1) ? o1 : o2;
  float scl = (seg == 0) ? 0.125f : 1.0f;
  int lc0 = nBase & 1023;
  // chunked C-stage: 128 rows at a time in LDS [128][264], then 16B stores
#pragma unroll
  for (int h = 0; h < 2; ++h) {
    if ((w >> 2) == h) {
#pragma unroll
      for (int jj = 0; jj < 4; ++jj) {
        float bvv = bp[lc0 + wc + jj * 16 + m];
#pragma unroll
        for (int i = 0; i < 8; ++i)
#pragma unroll
          for (int r = 0; r < 4; ++r)
            smu[(i * 16 + q4 * 4 + r) * 264 + wc + jj * 16 + m] =
                f2b((acc[i][jj][r] + bvv) * scl);
      }
    }
    __syncthreads();
#pragma unroll
    for (int rd = 0; rd < 8; ++rd) {
      int idx = rd * 512 + t;
      int row = idx >> 5, cs = (idx & 31) * 8;
      uint4 v = *(const uint4*)(smu + row * 264 + cs);
      *(uint4*)(ob + (size_t)(rowBase + h * 128 + row) * 1024 + lc0 + cs) = v;
    }
    __syncthreads();
  }
}

// ---------------------------------------------------------------------------
// In-place row LayerNorm on bf16 buffer (1024 cols, fp32 math).
// ---------------------------------------------------------------------------
__global__ __launch_bounds__(256) void ln_bf(unsigned short* __restrict__ buf,
    const float* __restrict__ g, const float* __restrict__ b) {
  int row = blockIdx.x;
  unsigned short* p = buf + (size_t)row * 1024;
  int tid = threadIdx.x;
  ushort4 u4 = ((const ushort4*)p)[tid];
  float x0 = b2f(u4.x), x1 = b2f(u4.y), x2 = b2f(u4.z), x3 = b2f(u4.w);
  float s = x0 + x1 + x2 + x3;
  float ss = x0 * x0 + x1 * x1 + x2 * x2 + x3 * x3;
#pragma unroll
  for (int off = 32; off > 0; off >>= 1) {
    s += __shfl_down(s, off);
    ss += __shfl_down(ss, off);
  }
  __shared__ float sred[8], ssred[8];
  int wave = tid >> 6, lane = tid & 63;
  if (lane == 0) { sred[wave] = s; ssred[wave] = ss; }
  __syncthreads();
  if (tid == 0) {
    float S = 0, SS = 0;
    for (int w = 0; w < 4; ++w) { S += sred[w]; SS += ssred[w]; }
    float m = S * (1.0f / 1024.0f);
    float v = SS * (1.0f / 1024.0f) - m * m;
    sred[0] = m;
    ssred[0] = rsqrtf(v + 1e-5f);
  }
  __syncthreads();
  float m = sred[0], rinv = ssred[0];
  float4 gg = ((const float4*)g)[tid];
  float4 bb = ((const float4*)b)[tid];
  ushort4 y;
  y.x = f2b((x0 - m) * rinv * gg.x + bb.x);
  y.y = f2b((x1 - m) * rinv * gg.y + bb.y);
  y.z = f2b((x2 - m) * rinv * gg.z + bb.z);
  y.w = f2b((x3 - m) * rinv * gg.w + bb.w);
  ((ushort4*)p)[tid] = y;
}

// ---------------------------------------------------------------------------
// Column softmax stats, phase A: per-chunk partials.
// ---------------------------------------------------------------------------
__global__ __launch_bounds__(256) void col_part(const float* __restrict__ yd,
    float* __restrict__ pm, float* __restrict__ ps) {
  int cg = blockIdx.x, b = blockIdx.y, sc = blockIdx.z;
  int t = threadIdx.x;
  int lane = t & 63, grp = t >> 6;
  const float* base = yd + (size_t)b * 4096 * 512 + (size_t)(sc * 256) * 512 +
                      cg * 64 + lane;
  float m = -1e30f, s = 0.f;
  for (int r = grp; r < 256; r += 4) {
    float x = base[(size_t)r * 512];
    float mn = fmaxf(m, x);
    s = s * expf(m - mn) + expf(x - mn);
    m = mn;
  }
  __shared__ float mS[4][64], sS[4][64];
  mS[grp][lane] = m;
  sS[grp][lane] = s;
  __syncthreads();
  if (grp == 0) {
    float M = mS[0][lane], S = sS[0][lane];
#pragma unroll
    for (int k = 1; k < 4; ++k) {
      float m2 = mS[k][lane], s2 = sS[k][lane];
      float Mn = fmaxf(M, m2);
      S = S * expf(M - Mn) + s2 * expf(m2 - Mn);
      M = Mn;
    }
    int col = cg * 64 + lane;
    pm[((size_t)(b * 512 + col)) * 16 + sc] = M;
    ps[((size_t)(b * 512 + col)) * 16 + sc] = S;
  }
}

// ---------------------------------------------------------------------------
// Column softmax stats, phase B: merge 16 partials per column.
// ---------------------------------------------------------------------------
__global__ __launch_bounds__(256) void col_combine(const float* __restrict__ pm,
    const float* __restrict__ ps, float* __restrict__ stats) {
  int idx = blockIdx.x * 256 + threadIdx.x;  // (b*512+col)
  float M = -1e30f, S = 0.f;
#pragma unroll
  for (int sc = 0; sc < 16; ++sc) {
    float m2 = pm[(size_t)idx * 16 + sc], s2 = ps[(size_t)idx * 16 + sc];
    float Mn = fmaxf(M, m2);
    S = S * expf(M - Mn) + s2 * expf(m2 - Mn);
    M = Mn;
  }
  stats[(size_t)idx * 2] = M;
  stats[(size_t)idx * 2 + 1] = 1.0f / S;
}

// ---------------------------------------------------------------------------
// Landmark compression partials; K/V bf16. (R1 LDS-staged outer product.)
// ---------------------------------------------------------------------------
#define NCHUNK 32
#define SCH    128
__global__ __launch_bounds__(256) void compress(const float* __restrict__ yd,
    const float* __restrict__ stats, const unsigned short* __restrict__ kbuf,
    const unsigned short* __restrict__ vbuf, float* __restrict__ kcp,
    float* __restrict__ vcp) {
  int c = blockIdx.x, h = blockIdx.y, b = blockIdx.z;
  int tid = threadIdx.x;
  int dq = tid & 15;     // output d = dq*4 .. dq*4+3
  int lp = tid >> 4;     // output l = lp*2, lp*2+1
  __shared__ float mxS[32], isS[32];
  __shared__ float pS[16][32];
  __shared__ float KfS[16][64];
  __shared__ float VfS[16][64];
  if (tid < 32) {
    mxS[tid] = stats[(size_t)(b * 512 + h * 32 + tid) * 2];
    isS[tid] = stats[(size_t)(b * 512 + h * 32 + tid) * 2 + 1];
  }
  __syncthreads();
  f32x4 aK0 = {}, aK1 = {}, aV0 = {}, aV1 = {};
  int s0 = c * SCH;
  for (int sc = 0; sc < SCH; sc += 16) {
    int bs = b * 4096 + s0 + sc;
    {
      int sl = tid >> 4;
      int l2 = (tid & 15) * 2;
      const float2 yv =
          *(const float2*)(yd + ((size_t)(bs + sl)) * 512 + h * 32 + l2);
      pS[sl][l2] = expf(yv.x - mxS[l2]) * isS[l2];
      pS[sl][l2 + 1] = expf(yv.y - mxS[l2 + 1]) * isS[l2 + 1];
      size_t roff = ((size_t)(bs + sl)) * 1024 + h * 64 + (tid & 15) * 4;
      ushort4 ku = *(const ushort4*)(kbuf + roff);
      ushort4 vu = *(const ushort4*)(vbuf + roff);
      f32x4 kf, vf;
      kf[0] = b2f(ku.x); kf[1] = b2f(ku.y); kf[2] = b2f(ku.z); kf[3] = b2f(ku.w);
      vf[0] = b2f(vu.x); vf[1] = b2f(vu.y); vf[2] = b2f(vu.z); vf[3] = b2f(vu.w);
      *(f32x4*)&KfS[sl][(tid & 15) * 4] = kf;
      *(f32x4*)&VfS[sl][(tid & 15) * 4] = vf;
    }
    __syncthreads();
#pragma unroll
    for (int sl = 0; sl < 16; ++sl) {
      float p0 = pS[sl][lp * 2];
      float p1 = pS[sl][lp * 2 + 1];
      const f32x4 kk = *(const f32x4*)&KfS[sl][dq * 4];
      const f32x4 vv = *(const f32x4*)&VfS[sl][dq * 4];
#pragma unroll
      for (int q = 0; q < 4; ++q) {
        aK0[q] += p0 * kk[q];
        aK1[q] += p1 * kk[q];
        aV0[q] += p0 * vv[q];
        aV1[q] += p1 * vv[q];
      }
    }
    __syncthreads();
  }
  size_t o0 = ((((size_t)c * 4 + b) * 16 + h) * 32 + (lp * 2)) * 64 + dq * 4;
  *(f32x4*)&kcp[o0] = aK0;
  *(f32x4*)&kcp[o0 + 64] = aK1;
  *(f32x4*)&vcp[o0] = aV0;
  *(f32x4*)&vcp[o0 + 64] = aV1;
}

// ---------------------------------------------------------------------------
// Reduce compression partials (32 chunks) + LayerNorm (fp32).
// ---------------------------------------------------------------------------
__global__ __launch_bounds__(256) void ln_compress(const float* __restrict__ kcp,
    const float* __restrict__ vcp, const float* __restrict__ g_s,
    const float* __restrict__ b_s, float* __restrict__ kc_ln,
    float* __restrict__ vc_ln) {
  int row = blockIdx.x;            // b*32 + l
  int b = row >> 5, l = row & 31;
  const float* part = blockIdx.y ? vcp : kcp;
  float* outp = blockIdx.y ? vc_ln : kc_ln;
  int tid = threadIdx.x;
  int h = tid >> 4, d4 = (tid & 15) * 4;
  size_t base = (((size_t)b * 16 + h) * 32 + l) * 64 + d4;
  f32x4 x = {};
#pragma unroll
  for (int cch = 0; cch < NCHUNK; ++cch) {
    const f32x4 v = *(const f32x4*)&part[base + (size_t)cch * 131072];
#pragma unroll
    for (int q = 0; q < 4; ++q) x[q] += v[q];
  }
  float lsum = x[0] + x[1] + x[2] + x[3];
  float lss = x[0] * x[0] + x[1] * x[1] + x[2] * x[2] + x[3] * x[3];
#pragma unroll
  for (int off = 32; off > 0; off >>= 1) {
    lsum += __shfl_down(lsum, off);
    lss += __shfl_down(lss, off);
  }
  __shared__ float red[8], red2[8];
  int wave = tid >> 6, lane = tid & 63;
  if (lane == 0) { red[wave] = lsum; red2[wave] = lss; }
  __syncthreads();
  if (tid == 0) {
    float S = 0, SS = 0;
    for (int w = 0; w < 4; ++w) { S += red[w]; SS += red2[w]; }
    float m = S * (1.0f / 1024.0f);
    float v = SS * (1.0f / 1024.0f) - m * m;
    red[0] = m;
    red2[0] = rsqrtf(v + 1e-5f);
  }
  __syncthreads();
  float m = red[0], rinv = red2[0];
  int j = tid * 4;  // == h*64 + d4
  const float4 gg = *(const float4*)(g_s + j);
  const float4 bb = *(const float4*)(b_s + j);
  float4 yo;
  yo.x = (x[0] - m) * rinv * gg.x + bb.x;
  yo.y = (x[1] - m) * rinv * gg.y + bb.y;
  yo.z = (x[2] - m) * rinv * gg.z + bb.z;
  yo.w = (x[3] - m) * rinv * gg.w + bb.w;
  *(float4*)(outp + (size_t)row * 1024 + j) = yo;
}

// ---------------------------------------------------------------------------
// Fused attention (R2: MFMA rewrite).
// ---------------------------------------------------------------------------
__global__ __launch_bounds__(256) void attention(unsigned short* __restrict__ qc,
    const unsigned short* __restrict__ kbuf,
    const unsigned short* __restrict__ vbuf,
    const float* __restrict__ kc_ln, const float* __restrict__ vc_ln) {
  int qt = blockIdx.x, h = blockIdx.y, b = blockIdx.z;
  int t = threadIdx.x;
  int l = t & 63, w = t >> 6;
  int lr16 = l & 15, q4 = l >> 4;
  int s0 = qt * 64, hoff = h * 64;

  __shared__ unsigned short regionA[12672];  // 25344 B
  __shared__ unsigned short Vt[64 * 128];    // 16384 B, XOR-swz k^((d&31)<<2)
  unsigned short* Qs = regionA;              // [64][72]
  unsigned short* Ks = regionA + 64 * 72;    // [112][72] (rows>=104 unused)
  unsigned short* Ps = regionA;              // alias: [64][128] swz blk^(q&7)
  unsigned short* Cs = regionA + 64 * 128;   // alias: [64][68]

  // ---- stage Q (64x64 bf16) ----
#pragma unroll
  for (int it = 0; it < 2; ++it) {
    int sid = it * 256 + t;
    int row = sid >> 3, seg = sid & 7;
    uint4 v = *(const uint4*)(qc + ((size_t)(b * 4096 + s0 + row)) * 1024 +
                              hoff + seg * 8);
    *(uint4*)(Qs + row * 72 + seg * 8) = v;
  }
  // ---- stage Kc (32x64 fp32 -> bf16), rows 0..31 of Ks ----
#pragma unroll
  for (int it = 0; it < 2; ++it) {
    int sid = it * 256 + t;
    int row = sid >> 4, s4 = sid & 15;
    float4 v = *(const float4*)(kc_ln + ((size_t)(b * 32 + row)) * 1024 +
                                hoff + s4 * 4);
    ushort4 u = make_ushort4(f2b(v.x), f2b(v.y), f2b(v.z), f2b(v.w));
    *(ushort4*)(Ks + row * 72 + s4 * 4) = u;
  }
  // ---- stage Kw (72 window rows), rows 32..103 of Ks ----
#pragma unroll
  for (int it = 0; it < 3; ++it) {
    int sid = it * 256 + t;
    if (sid < 576) {
      int r = sid >> 3, seg = sid & 7;
      int pos = s0 - 4 + r;
      uint4 v = {0, 0, 0, 0};
      if (pos >= 0 && pos < 4096)
        v = *(const uint4*)(kbuf + ((size_t)(b * 4096 + pos)) * 1024 + hoff +
                            seg * 8);
      *(uint4*)(Ks + (32 + r) * 72 + seg * 8) = v;
    }
  }
  // ---- stage Vt (transposed, 64 d x 128 k-slots; slots>=104 zero) ----
#pragma unroll
  for (int it = 0; it < 8; ++it) {
    int d = t & 63;
    int k0 = (t >> 6) * 4 + it * 16;
    unsigned short vv[4];
#pragma unroll
    for (int i = 0; i < 4; ++i) {
      int kk = k0 + i;
      unsigned short x = 0;
      if (kk < 32) {
        x = f2b(vc_ln[((size_t)(b * 32 + kk)) * 1024 + hoff + d]);
      } else if (kk < 104) {
        int pos = s0 - 4 + (kk - 32);
        if (pos >= 0 && pos < 4096)
          x = vbuf[((size_t)(b * 4096 + pos)) * 1024 + hoff + d];
      }
      vv[i] = x;
    }
    *(ushort4*)(Vt + d * 128 + (k0 ^ ((d & 31) << 2))) = *(ushort4*)vv;
  }
  __syncthreads();

  // ---- QK^T: wave w handles queries mbase..mbase+15 ----
  int mbase = w * 16;
  bf16x8 aq[2];
#pragma unroll
  for (int ks = 0; ks < 2; ++ks)
    aq[ks] = *(const bf16x8*)(Qs + (mbase + lr16) * 72 + ks * 32 + q4 * 8);
  f32x4 S[7];
#pragma unroll
  for (int nb = 0; nb < 7; ++nb) {
    f32x4 acc = {};
#pragma unroll
    for (int ks = 0; ks < 2; ++ks) {
      bf16x8 bk =
          *(const bf16x8*)(Ks + (nb * 16 + lr16) * 72 + ks * 32 + q4 * 8);
      acc = __builtin_amdgcn_mfma_f32_16x16x32_bf16(aq[ks], bk, acc, 0, 0, 0);
    }
    S[nb] = acc;
  }

  // ---- mask + softmax in-register ----
  float ex[7][4];
#pragma unroll
  for (int r = 0; r < 4; ++r) {
    int qrow = mbase + q4 * 4 + r;        // block-local query 0..63
    int g8 = (qrow >> 3) * 8;
    float m = -1e30f;
#pragma unroll
    for (int nb = 0; nb < 7; ++nb) {
      int col = nb * 16 + lr16;
      float v = S[nb][r];
      if (col >= 32) {
        int rw = col - 32;
        int pos = s0 - 4 + rw;
        bool ok = (rw >= g8) && (rw < g8 + 16) && (pos >= 0) && (pos < 4096);
        if (!ok) v = -INFINITY;
      }
      ex[nb][r] = v;
      m = fmaxf(m, v);
    }
    m = fmaxf(m, __shfl_xor(m, 1));
    m = fmaxf(m, __shfl_xor(m, 2));
    m = fmaxf(m, __shfl_xor(m, 4));
    m = fmaxf(m, __shfl_xor(m, 8));
    float s = 0.f;
#pragma unroll
    for (int nb = 0; nb < 7; ++nb) {
      float e = expf(ex[nb][r] - m);
      ex[nb][r] = e;
      s += e;
    }
    s += __shfl_xor(s, 1);
    s += __shfl_xor(s, 2);
    s += __shfl_xor(s, 4);
    s += __shfl_xor(s, 8);
    float inv = 1.0f / s;
#pragma unroll
    for (int nb = 0; nb < 7; ++nb) ex[nb][r] *= inv;
  }
  __syncthreads();   // all QK reads of Qs/Ks done; regionA now P/C

  // zero P pad cols 112..127 (swizzled blocks 14,15 per row)
  if (t < 128) {
    int q = t >> 1, blk = 14 + (t & 1);
    uint4 z = {0, 0, 0, 0};
    *(uint4*)(Ps + q * 128 + ((blk ^ (q & 7)) << 3)) = z;
  }
  // write P bf16 (swizzled 16B blocks)
#pragma unroll
  for (int r = 0; r < 4; ++r) {
    int q = mbase + q4 * 4 + r;
#pragma unroll
    for (int nb = 0; nb < 7; ++nb) {
      int col = nb * 16 + lr16;
      int blk = col >> 3;
      Ps[q * 128 + ((blk ^ (q & 7)) << 3) + (col & 7)] = f2b(ex[nb][r]);
    }
  }
  __syncthreads();

  // ---- PV: C[q][d] = sum_k P[q][k] * V[k][d] ----
  bf16x8 pa[4];
#pragma unroll
  for (int ks = 0; ks < 4; ++ks) {
    int q = mbase + lr16;
    int blk = ks * 4 + q4;
    pa[ks] = *(const bf16x8*)(Ps + q * 128 + ((blk ^ (q & 7)) << 3));
  }
#pragma unroll
  for (int nb = 0; nb < 4; ++nb) {
    f32x4 acc = {};
    int d = nb * 16 + lr16;
#pragma unroll
    for (int ks = 0; ks < 4; ++ks) {
      unsigned short vv[8];
#pragma unroll
      for (int jh = 0; jh < 2; ++jh) {
        int k4 = ks * 32 + q4 * 8 + jh * 4;
        *(ushort4*)(vv + jh * 4) =
            *(const ushort4*)(Vt + d * 128 + (k4 ^ ((d & 31) << 2)));
      }
      acc = __builtin_amdgcn_mfma_f32_16x16x32_bf16(pa[ks], *(const bf16x8*)vv,
                                                    acc, 0, 0, 0);
    }
#pragma unroll
    for (int r = 0; r < 4; ++r) {
      int row = mbase + q4 * 4 + r;
      Cs[row * 68 + d] = f2b(acc[r]);
    }
  }
  __syncthreads();

  // ---- store C (coalesced 16B) ----
#pragma unroll
  for (int it = 0; it < 2; ++it) {
    int sid = it * 256 + t;
    int row = sid >> 3, seg = sid & 7;
    ushort4 a0 = *(const ushort4*)(Cs + row * 68 + seg * 8);
    ushort4 a1 = *(const ushort4*)(Cs + row * 68 + seg * 8 + 4);
    unsigned short u[8];
    *(ushort4*)u = a0;
    *(ushort4*)(u + 4) = a1;
    *(uint4*)(qc + ((size_t)(b * 4096 + s0 + row)) * 1024 + hoff + seg * 8) =
        *(uint4*)u;
  }
}

// ---------------------------------------------------------------------------
extern "C" void kernel_launch(void* const* d_in, const int* in_sizes, int n_in,
                              void* d_out, int out_size, void* d_ws,
                              size_t ws_size, hipStream_t stream) {
  const float* query = (const float*)d_in[0];
  const float* Wq = (const float*)d_in[1];
  const float* bq = (const float*)d_in[2];
  const float* Wk = (const float*)d_in[3];
  const float* bk = (const float*)d_in[4];
  const float* Wv = (const float*)d_in[5];
  const float* bv = (const float*)d_in[6];
  const float* Wo = (const float*)d_in[7];
  const float* bo = (const float*)d_in[8];
  const float* g_l = (const float*)d_in[9];
  const float* b_l = (const float*)d_in[10];
  const float* g_s = (const float*)d_in[11];
  const float* b_s = (const float*)d_in[12];
  const float* Wd = (const float*)d_in[13];
  const float* bd = (const float*)d_in[14];
  float* out = (float*)d_out;

  // allow >64KB dynamic LDS for gemm256 (once per process)
  static bool attr_set = []() {
    hipFuncSetAttribute((const void*)gemm256,
                        hipFuncAttributeMaxDynamicSharedMemorySize, 135168);
    return true;
  }();
  (void)attr_set;

  // Workspace layout (~205 MB)
  unsigned short* qb = (unsigned short*)d_ws;  // 16,777,216 bf16 (Q, then C)
  unsigned short* kb = qb + 16777216;          // 16,777,216 bf16
  unsigned short* vb = kb + 16777216;          // 16,777,216 bf16
  unsigned short* xb = vb + 16777216;          // 16,777,216 bf16 (X)
  float* yd = (float*)(xb + 16777216);         // 8,388,608 fp32
  float* stats = yd + 8388608;                 // 4,096
  float* col_pm = stats + 4096;                // 32,768
  float* col_ps = col_pm + 32768;              // 32,768
  float* kc_part = col_ps + 32768;             // 4,194,304 (32 chunks)
  float* vc_part = kc_part + 4194304;          // 4,194,304
  float* kc_ln = vc_part + 4194304;            // 131,072
  float* vc_ln = kc_ln + 131072;               // 131,072
  // wAll: concatenated [WqT|WkT|WvT|WdT] rows (1024+1024+1024+512 = 3584)
  unsigned short* wAll = (unsigned short*)(vc_ln + 131072);  // 3,670,016
  unsigned short* woT = wAll + 3670016;        // 1,048,576

  dim3 blk(256);
  // bf16 conversions
  conv_rows<<<16384, blk, 0, stream>>>(query, xb);
  conv_wT_all<<<dim3(32, 32, 5), blk, 0, stream>>>(Wq, Wk, Wv, Wd, Wo,
                                                   wAll, woT);
  // Fused QKVD projections: 256^2 tiles, BK=32, quad-buffer depth-3 pipeline
  gemm256<<<896, dim3(512), 131072, stream>>>(xb, wAll, bq, bk, bv, bd,
                                              qb, kb, vb, yd, nullptr, 0);
  // LN K and V in one dispatch (kb,vb contiguous)
  ln_bf<<<32768, blk, 0, stream>>>(kb, g_l, b_l);
  // head-score softmax stats (two-phase, 512-block parallel)
  col_part<<<dim3(8, 4, 16), blk, 0, stream>>>(yd, col_pm, col_ps);
  col_combine<<<8, blk, 0, stream>>>(col_pm, col_ps, stats);
  // landmark compression + LN
  compress<<<dim3(NCHUNK, 16, 4), blk, 0, stream>>>(yd, stats, kb, vb,
                                                    kc_part, vc_part);
  ln_compress<<<dim3(128, 2), blk, 0, stream>>>(kc_part, vc_part, g_s, b_s,
                                                kc_ln, vc_ln);
  // fused attention (bf16 C overwrites qb)
  attention<<<dim3(64, 16, 4), blk, 0, stream>>>(qb, kb, vb, kc_ln, vc_ln);
  // output projection (+ (b,s)->(s,b) remap), reads bf16 C directly
  gemm256<<<256, dim3(512), 131072, stream>>>(qb, woT, bo, nullptr, nullptr,
                                              nullptr, nullptr, nullptr,
                                              nullptr, nullptr, out, 1);
}

// Round 7
// 493.399 us; speedup vs baseline: 1.0574x; 1.0235x over previous
//
#include <hip/hip_runtime.h>
#include <cstddef>
#include <cstdint>

// Problem constants
#define DIMC 1024
#define HC   16
#define DHC  64
#define LC   32
#define WC   8
#define EC   4
#define SEQC 4096
#define BC   4
#define MTOT 16384    // B * SEQ

typedef __attribute__((ext_vector_type(8))) __bf16 bf16x8;
typedef __attribute__((ext_vector_type(4))) float f32x4;

__device__ inline unsigned short f2b(float f) {
  unsigned int u = __float_as_uint(f);
  u += 0x7fff + ((u >> 16) & 1);   // round-to-nearest-even
  return (unsigned short)(u >> 16);
}
__device__ inline float b2f(unsigned short u) {
  return __uint_as_float(((unsigned int)u) << 16);
}

// async global->LDS, 16B/lane; LDS dest = wave-uniform base + lane*16.
__device__ inline void gll16(const void* g, void* l) {
  __builtin_amdgcn_global_load_lds(
      (__attribute__((address_space(1))) void*)g,
      (__attribute__((address_space(3))) void*)l, 16, 0, 0);
}

// ---------------------------------------------------------------------------
// Row convert fp32 -> bf16 with (s,b,.)->(b,s,.) transpose folded in.
// ---------------------------------------------------------------------------
__global__ __launch_bounds__(256) void conv_rows(const float* __restrict__ src,
    unsigned short* __restrict__ dst) {
  int r = blockIdx.x;
  int sr = ((r & 4095) << 2) | (r >> 12);
  const float4* s = (const float4*)(src + (size_t)sr * 1024);
  ushort4* d = (ushort4*)(dst + (size_t)r * 1024);
  int t = threadIdx.x;
  float4 v = s[t];
  d[t] = make_ushort4(f2b(v.x), f2b(v.y), f2b(v.z), f2b(v.w));
}

// ---------------------------------------------------------------------------
// All weight transposes in one dispatch. z: 0=Wq 1=Wk 2=Wv 3=Wd 4=Wo.
// ---------------------------------------------------------------------------
__global__ __launch_bounds__(256) void conv_wT_all(
    const float* __restrict__ Wq, const float* __restrict__ Wk,
    const float* __restrict__ Wv, const float* __restrict__ Wd,
    const float* __restrict__ Wo, unsigned short* __restrict__ wAll,
    unsigned short* __restrict__ woT) {
  __shared__ float tile[32][33];
  int z = blockIdx.z;
  const float* W = (z == 0) ? Wq : (z == 1) ? Wk : (z == 2) ? Wv
                   : (z == 3) ? Wd : Wo;
  unsigned short* WT = (z == 4) ? woT : (wAll + (size_t)z * 1048576);
  int N = (z == 3) ? 512 : 1024;
  int n0 = blockIdx.x * 32, k0 = blockIdx.y * 32;
  if (n0 >= N) return;
  int t = threadIdx.x;
  int tr = t >> 5, tc = t & 31;
#pragma unroll
  for (int i = 0; i < 4; ++i)
    tile[tr + i * 8][tc] = W[(size_t)(k0 + tr + i * 8) * N + n0 + tc];
  __syncthreads();
#pragma unroll
  for (int i = 0; i < 4; ++i)
    WT[(size_t)(n0 + tr + i * 8) * 1024 + k0 + tc] = f2b(tile[tc][tr + i * 8]);
}

// ---------------------------------------------------------------------------
// 256x128 bf16 MFMA GEMM (R7): 8 waves (512 thr) as 4x2, per-wave 64x64
// output -> acc = 64 VGPRs; __launch_bounds__(512,4) caps regs at 128 so
// TWO blocks co-reside per CU (4 waves/SIMD) -- independent blocks give
// unaligned barriers, so one block's MFMA covers the other's stage window
// (m114 mechanism). LDS 72 KB = 3 rotating buffers x (A 16K + B 8K),
// stage-at-top depth-2, counted vmcnt(3). Zero-conflict XOR swizzle via
// pre-swizzled global source (same scheme as R5/R6, measured 0 conflicts).
// Race-freedom: STAGE(kt+2 -> buf[(kt+2)%3]); that buffer was last read in
// iteration kt-1, which ended at a barrier BEFORE these loads are issued.
// mode 0: QKVD fused epilogue (one segment per block; bf16 via LDS-staged
// 16B stores, fp32 yd direct). mode 1: fp32 out + (b,s)->(s,b) remap.
// ---------------------------------------------------------------------------
__global__ __launch_bounds__(512, 4) void gemm128(
    const unsigned short* __restrict__ A, const unsigned short* __restrict__ BT,
    const float* __restrict__ b0, const float* __restrict__ b1,
    const float* __restrict__ b2, const float* __restrict__ b3,
    unsigned short* __restrict__ o0, unsigned short* __restrict__ o1,
    unsigned short* __restrict__ o2, float* __restrict__ oy,
    float* __restrict__ outf, int mode) {
  extern __shared__ char smb[];
  unsigned short* smu = (unsigned short*)smb;
  int t = threadIdx.x;
  int w = t >> 6, lane = t & 63;
  int m = lane & 15, q4 = lane >> 4;
  int wr = (w >> 1) * 64, wc = (w & 1) * 64;
  int id = blockIdx.x;
  // XCD-chunked: rowT fast within XCD, colT slow (A panel L2-resident)
  int rowT = (id & 7) * 8 + ((id >> 3) & 7);
  int colT = id >> 6;
  int rowBase = rowT * 256, nBase = colT * 128;

  // staging: 3 gll16/thread/tile (A rows 0-127, A rows 128-255, B rows 0-127)
  // source granule pre-swizzled so LDS stays linear; LDS(row,slot) holds
  // global granule slot ^ ((row>>1)&3).
  int srow = t >> 2;                               // 0..127
  int gsw = ((t & 3) ^ ((t >> 3) & 3)) * 8;        // ushorts
  const unsigned short* gA0 = A + (size_t)(rowBase + srow) * 1024 + gsw;
  const unsigned short* gA1 = A + (size_t)(rowBase + 128 + srow) * 1024 + gsw;
  const unsigned short* gB0 = BT + (size_t)(nBase + srow) * 1024 + gsw;
  int ldsW = w * 1024;                             // bytes, wave-uniform
  // fragment read swizzle: slot = q4 ^ ((m>>1)&3)
  int sx = (q4 ^ ((m >> 1) & 3)) * 8;
  f32x4 acc[4][4] = {};

#define STAGE7(kt_, c_)                                          \
  {                                                              \
    int kc_ = (kt_) * 32;                                        \
    gll16(gA0 + kc_, smb + (c_) * 24576 + ldsW);                 \
    gll16(gA1 + kc_, smb + (c_) * 24576 + 8192 + ldsW);          \
    gll16(gB0 + kc_, smb + (c_) * 24576 + 16384 + ldsW);         \
  }

  // prologue: tiles 0,1 into buffers 0,1 (6 loads); wait tile 0's 3.
  STAGE7(0, 0);
  STAGE7(1, 1);
  asm volatile("s_waitcnt vmcnt(3)" ::: "memory");
  __builtin_amdgcn_s_barrier();
  __builtin_amdgcn_sched_barrier(0);

  for (int kt = 0; kt < 32; ++kt) {
    int c = kt % 3;
    if (kt < 30) STAGE7(kt + 2, (kt + 2) % 3);
    const unsigned short* Au = smu + c * 12288;
    const unsigned short* Bu = smu + c * 12288 + 8192;
    bf16x8 bfB[4];
#pragma unroll
    for (int jj = 0; jj < 4; ++jj)
      bfB[jj] = *(const bf16x8*)(Bu + (wc + jj * 16 + m) * 32 + sx);
    bf16x8 afA[4];
#pragma unroll
    for (int mi = 0; mi < 4; ++mi)
      afA[mi] = *(const bf16x8*)(Au + (wr + mi * 16 + m) * 32 + sx);
    __builtin_amdgcn_s_setprio(1);
#pragma unroll
    for (int mi = 0; mi < 4; ++mi)
#pragma unroll
      for (int jj = 0; jj < 4; ++jj)
        acc[mi][jj] = __builtin_amdgcn_mfma_f32_16x16x32_bf16(
            afA[mi], bfB[jj], acc[mi][jj], 0, 0, 0);
    __builtin_amdgcn_s_setprio(0);
    if (kt == 31) break;
    if (kt < 30) {
      asm volatile("s_waitcnt vmcnt(3)" ::: "memory");   // drain tile kt+1
    } else {
      asm volatile("s_waitcnt vmcnt(0)" ::: "memory");   // drain tile 31
    }
    __builtin_amdgcn_s_barrier();
    __builtin_amdgcn_sched_barrier(0);
  }
  __syncthreads();

  // ---------------- epilogue ----------------
  if (mode == 1) {
#pragma unroll
    for (int jj = 0; jj < 4; ++jj) {
      int col = nBase + wc + jj * 16 + m;
      float bvv = b0[col];
#pragma unroll
      for (int mi = 0; mi < 4; ++mi)
#pragma unroll
        for (int r = 0; r < 4; ++r) {
          int rr = rowBase + wr + mi * 16 + q4 * 4 + r;
          int orow = ((rr & 4095) << 2) | (rr >> 12);
          outf[(size_t)orow * 1024 + col] = acc[mi][jj][r] + bvv;
        }
    }
    return;
  }
  int seg = nBase >> 10;      // uniform per block (128-col tile in 1 segment)
  if (seg == 3) {             // head-score fp32 segment (N=512)
    int lc0 = nBase - 3072;
#pragma unroll
    for (int jj = 0; jj < 4; ++jj) {
      float bvv = b3[lc0 + wc + jj * 16 + m];
#pragma unroll
      for (int mi = 0; mi < 4; ++mi)
#pragma unroll
        for (int r = 0; r < 4; ++r)
          oy[(size_t)(rowBase + wr + mi * 16 + q4 * 4 + r) * 512 + lc0 + wc +
             jj * 16 + m] = acc[mi][jj][r] + bvv;
    }
    return;
  }
  const float* bp = (seg == 0) ? b0 : (seg == 1) ? b1 : b2;
  unsigned short* ob = (seg == 0) ? o0 : (seg == 1) ? o1 : o2;
  float scl = (seg == 0) ? 0.125f : 1.0f;
  int lc0 = nBase & 1023;
  // stage C 256x128 bf16 in LDS (stride 136 spreads banks), then 16B stores
#pragma unroll
  for (int jj = 0; jj < 4; ++jj) {
    float bvv = bp[lc0 + wc + jj * 16 + m];
#pragma unroll
    for (int mi = 0; mi < 4; ++mi)
#pragma unroll
      for (int r = 0; r < 4; ++r)
        smu[(wr + mi * 16 + q4 * 4 + r) * 136 + wc + jj * 16 + m] =
            f2b((acc[mi][jj][r] + bvv) * scl);
  }
  __syncthreads();
#pragma unroll
  for (int rd = 0; rd < 8; ++rd) {
    int idx = rd * 512 + t;
    int row = idx >> 4, cs = (idx & 15) * 8;
    uint4 v = *(const uint4*)(smu + row * 136 + cs);
    *(uint4*)(ob + (size_t)(rowBase + row) * 1024 + lc0 + cs) = v;
  }
}

// ---------------------------------------------------------------------------
// In-place row LayerNorm on bf16 buffer (1024 cols, fp32 math).
// ---------------------------------------------------------------------------
__global__ __launch_bounds__(256) void ln_bf(unsigned short* __restrict__ buf,
    const float* __restrict__ g, const float* __restrict__ b) {
  int row = blockIdx.x;
  unsigned short* p = buf + (size_t)row * 1024;
  int tid = threadIdx.x;
  ushort4 u4 = ((const ushort4*)p)[tid];
  float x0 = b2f(u4.x), x1 = b2f(u4.y), x2 = b2f(u4.z), x3 = b2f(u4.w);
  float s = x0 + x1 + x2 + x3;
  float ss = x0 * x0 + x1 * x1 + x2 * x2 + x3 * x3;
#pragma unroll
  for (int off = 32; off > 0; off >>= 1) {
    s += __shfl_down(s, off);
    ss += __shfl_down(ss, off);
  }
  __shared__ float sred[8], ssred[8];
  int wave = tid >> 6, lane = tid & 63;
  if (lane == 0) { sred[wave] = s; ssred[wave] = ss; }
  __syncthreads();
  if (tid == 0) {
    float S = 0, SS = 0;
    for (int w = 0; w < 4; ++w) { S += sred[w]; SS += ssred[w]; }
    float m = S * (1.0f / 1024.0f);
    float v = SS * (1.0f / 1024.0f) - m * m;
    sred[0] = m;
    ssred[0] = rsqrtf(v + 1e-5f);
  }
  __syncthreads();
  float m = sred[0], rinv = ssred[0];
  float4 gg = ((const float4*)g)[tid];
  float4 bb = ((const float4*)b)[tid];
  ushort4 y;
  y.x = f2b((x0 - m) * rinv * gg.x + bb.x);
  y.y = f2b((x1 - m) * rinv * gg.y + bb.y);
  y.z = f2b((x2 - m) * rinv * gg.z + bb.z);
  y.w = f2b((x3 - m) * rinv * gg.w + bb.w);
  ((ushort4*)p)[tid] = y;
}

// ---------------------------------------------------------------------------
// Column softmax stats, phase A: per-chunk partials.
// ---------------------------------------------------------------------------
__global__ __launch_bounds__(256) void col_part(const float* __restrict__ yd,
    float* __restrict__ pm, float* __restrict__ ps) {
  int cg = blockIdx.x, b = blockIdx.y, sc = blockIdx.z;
  int t = threadIdx.x;
  int lane = t & 63, grp = t >> 6;
  const float* base = yd + (size_t)b * 4096 * 512 + (size_t)(sc * 256) * 512 +
                      cg * 64 + lane;
  float m = -1e30f, s = 0.f;
  for (int r = grp; r < 256; r += 4) {
    float x = base[(size_t)r * 512];
    float mn = fmaxf(m, x);
    s = s * expf(m - mn) + expf(x - mn);
    m = mn;
  }
  __shared__ float mS[4][64], sS[4][64];
  mS[grp][lane] = m;
  sS[grp][lane] = s;
  __syncthreads();
  if (grp == 0) {
    float M = mS[0][lane], S = sS[0][lane];
#pragma unroll
    for (int k = 1; k < 4; ++k) {
      float m2 = mS[k][lane], s2 = sS[k][lane];
      float Mn = fmaxf(M, m2);
      S = S * expf(M - Mn) + s2 * expf(m2 - Mn);
      M = Mn;
    }
    int col = cg * 64 + lane;
    pm[((size_t)(b * 512 + col)) * 16 + sc] = M;
    ps[((size_t)(b * 512 + col)) * 16 + sc] = S;
  }
}

// ---------------------------------------------------------------------------
// Column softmax stats, phase B: merge 16 partials per column.
// ---------------------------------------------------------------------------
__global__ __launch_bounds__(256) void col_combine(const float* __restrict__ pm,
    const float* __restrict__ ps, float* __restrict__ stats) {
  int idx = blockIdx.x * 256 + threadIdx.x;  // (b*512+col)
  float M = -1e30f, S = 0.f;
#pragma unroll
  for (int sc = 0; sc < 16; ++sc) {
    float m2 = pm[(size_t)idx * 16 + sc], s2 = ps[(size_t)idx * 16 + sc];
    float Mn = fmaxf(M, m2);
    S = S * expf(M - Mn) + s2 * expf(m2 - Mn);
    M = Mn;
  }
  stats[(size_t)idx * 2] = M;
  stats[(size_t)idx * 2 + 1] = 1.0f / S;
}

// ---------------------------------------------------------------------------
// Landmark compression partials; K/V bf16. (R1 LDS-staged outer product.)
// ---------------------------------------------------------------------------
#define NCHUNK 32
#define SCH    128
__global__ __launch_bounds__(256) void compress(const float* __restrict__ yd,
    const float* __restrict__ stats, const unsigned short* __restrict__ kbuf,
    const unsigned short* __restrict__ vbuf, float* __restrict__ kcp,
    float* __restrict__ vcp) {
  int c = blockIdx.x, h = blockIdx.y, b = blockIdx.z;
  int tid = threadIdx.x;
  int dq = tid & 15;     // output d = dq*4 .. dq*4+3
  int lp = tid >> 4;     // output l = lp*2, lp*2+1
  __shared__ float mxS[32], isS[32];
  __shared__ float pS[16][32];
  __shared__ float KfS[16][64];
  __shared__ float VfS[16][64];
  if (tid < 32) {
    mxS[tid] = stats[(size_t)(b * 512 + h * 32 + tid) * 2];
    isS[tid] = stats[(size_t)(b * 512 + h * 32 + tid) * 2 + 1];
  }
  __syncthreads();
  f32x4 aK0 = {}, aK1 = {}, aV0 = {}, aV1 = {};
  int s0 = c * SCH;
  for (int sc = 0; sc < SCH; sc += 16) {
    int bs = b * 4096 + s0 + sc;
    {
      int sl = tid >> 4;
      int l2 = (tid & 15) * 2;
      const float2 yv =
          *(const float2*)(yd + ((size_t)(bs + sl)) * 512 + h * 32 + l2);
      pS[sl][l2] = expf(yv.x - mxS[l2]) * isS[l2];
      pS[sl][l2 + 1] = expf(yv.y - mxS[l2 + 1]) * isS[l2 + 1];
      size_t roff = ((size_t)(bs + sl)) * 1024 + h * 64 + (tid & 15) * 4;
      ushort4 ku = *(const ushort4*)(kbuf + roff);
      ushort4 vu = *(const ushort4*)(vbuf + roff);
      f32x4 kf, vf;
      kf[0] = b2f(ku.x); kf[1] = b2f(ku.y); kf[2] = b2f(ku.z); kf[3] = b2f(ku.w);
      vf[0] = b2f(vu.x); vf[1] = b2f(vu.y); vf[2] = b2f(vu.z); vf[3] = b2f(vu.w);
      *(f32x4*)&KfS[sl][(tid & 15) * 4] = kf;
      *(f32x4*)&VfS[sl][(tid & 15) * 4] = vf;
    }
    __syncthreads();
#pragma unroll
    for (int sl = 0; sl < 16; ++sl) {
      float p0 = pS[sl][lp * 2];
      float p1 = pS[sl][lp * 2 + 1];
      const f32x4 kk = *(const f32x4*)&KfS[sl][dq * 4];
      const f32x4 vv = *(const f32x4*)&VfS[sl][dq * 4];
#pragma unroll
      for (int q = 0; q < 4; ++q) {
        aK0[q] += p0 * kk[q];
        aK1[q] += p1 * kk[q];
        aV0[q] += p0 * vv[q];
        aV1[q] += p1 * vv[q];
      }
    }
    __syncthreads();
  }
  size_t o0 = ((((size_t)c * 4 + b) * 16 + h) * 32 + (lp * 2)) * 64 + dq * 4;
  *(f32x4*)&kcp[o0] = aK0;
  *(f32x4*)&kcp[o0 + 64] = aK1;
  *(f32x4*)&vcp[o0] = aV0;
  *(f32x4*)&vcp[o0 + 64] = aV1;
}

// ---------------------------------------------------------------------------
// Reduce compression partials (32 chunks) + LayerNorm (fp32).
// ---------------------------------------------------------------------------
__global__ __launch_bounds__(256) void ln_compress(const float* __restrict__ kcp,
    const float* __restrict__ vcp, const float* __restrict__ g_s,
    const float* __restrict__ b_s, float* __restrict__ kc_ln,
    float* __restrict__ vc_ln) {
  int row = blockIdx.x;            // b*32 + l
  int b = row >> 5, l = row & 31;
  const float* part = blockIdx.y ? vcp : kcp;
  float* outp = blockIdx.y ? vc_ln : kc_ln;
  int tid = threadIdx.x;
  int h = tid >> 4, d4 = (tid & 15) * 4;
  size_t base = (((size_t)b * 16 + h) * 32 + l) * 64 + d4;
  f32x4 x = {};
#pragma unroll
  for (int cch = 0; cch < NCHUNK; ++cch) {
    const f32x4 v = *(const f32x4*)&part[base + (size_t)cch * 131072];
#pragma unroll
    for (int q = 0; q < 4; ++q) x[q] += v[q];
  }
  float lsum = x[0] + x[1] + x[2] + x[3];
  float lss = x[0] * x[0] + x[1] * x[1] + x[2] * x[2] + x[3] * x[3];
#pragma unroll
  for (int off = 32; off > 0; off >>= 1) {
    lsum += __shfl_down(lsum, off);
    lss += __shfl_down(lss, off);
  }
  __shared__ float red[8], red2[8];
  int wave = tid >> 6, lane = tid & 63;
  if (lane == 0) { red[wave] = lsum; red2[wave] = lss; }
  __syncthreads();
  if (tid == 0) {
    float S = 0, SS = 0;
    for (int w = 0; w < 4; ++w) { S += red[w]; SS += red2[w]; }
    float m = S * (1.0f / 1024.0f);
    float v = SS * (1.0f / 1024.0f) - m * m;
    red[0] = m;
    red2[0] = rsqrtf(v + 1e-5f);
  }
  __syncthreads();
  float m = red[0], rinv = red2[0];
  int j = tid * 4;  // == h*64 + d4
  const float4 gg = *(const float4*)(g_s + j);
  const float4 bb = *(const float4*)(b_s + j);
  float4 yo;
  yo.x = (x[0] - m) * rinv * gg.x + bb.x;
  yo.y = (x[1] - m) * rinv * gg.y + bb.y;
  yo.z = (x[2] - m) * rinv * gg.z + bb.z;
  yo.w = (x[3] - m) * rinv * gg.w + bb.w;
  *(float4*)(outp + (size_t)row * 1024 + j) = yo;
}

// ---------------------------------------------------------------------------
// Fused attention (R2: MFMA rewrite).
// ---------------------------------------------------------------------------
__global__ __launch_bounds__(256) void attention(unsigned short* __restrict__ qc,
    const unsigned short* __restrict__ kbuf,
    const unsigned short* __restrict__ vbuf,
    const float* __restrict__ kc_ln, const float* __restrict__ vc_ln) {
  int qt = blockIdx.x, h = blockIdx.y, b = blockIdx.z;
  int t = threadIdx.x;
  int l = t & 63, w = t >> 6;
  int lr16 = l & 15, q4 = l >> 4;
  int s0 = qt * 64, hoff = h * 64;

  __shared__ unsigned short regionA[12672];  // 25344 B
  __shared__ unsigned short Vt[64 * 128];    // 16384 B, XOR-swz k^((d&31)<<2)
  unsigned short* Qs = regionA;              // [64][72]
  unsigned short* Ks = regionA + 64 * 72;    // [112][72] (rows>=104 unused)
  unsigned short* Ps = regionA;              // alias: [64][128] swz blk^(q&7)
  unsigned short* Cs = regionA + 64 * 128;   // alias: [64][68]

  // ---- stage Q (64x64 bf16) ----
#pragma unroll
  for (int it = 0; it < 2; ++it) {
    int sid = it * 256 + t;
    int row = sid >> 3, seg = sid & 7;
    uint4 v = *(const uint4*)(qc + ((size_t)(b * 4096 + s0 + row)) * 1024 +
                              hoff + seg * 8);
    *(uint4*)(Qs + row * 72 + seg * 8) = v;
  }
  // ---- stage Kc (32x64 fp32 -> bf16), rows 0..31 of Ks ----
#pragma unroll
  for (int it = 0; it < 2; ++it) {
    int sid = it * 256 + t;
    int row = sid >> 4, s4 = sid & 15;
    float4 v = *(const float4*)(kc_ln + ((size_t)(b * 32 + row)) * 1024 +
                                hoff + s4 * 4);
    ushort4 u = make_ushort4(f2b(v.x), f2b(v.y), f2b(v.z), f2b(v.w));
    *(ushort4*)(Ks + row * 72 + s4 * 4) = u;
  }
  // ---- stage Kw (72 window rows), rows 32..103 of Ks ----
#pragma unroll
  for (int it = 0; it < 3; ++it) {
    int sid = it * 256 + t;
    if (sid < 576) {
      int r = sid >> 3, seg = sid & 7;
      int pos = s0 - 4 + r;
      uint4 v = {0, 0, 0, 0};
      if (pos >= 0 && pos < 4096)
        v = *(const uint4*)(kbuf + ((size_t)(b * 4096 + pos)) * 1024 + hoff +
                            seg * 8);
      *(uint4*)(Ks + (32 + r) * 72 + seg * 8) = v;
    }
  }
  // ---- stage Vt (transposed, 64 d x 128 k-slots; slots>=104 zero) ----
#pragma unroll
  for (int it = 0; it < 8; ++it) {
    int d = t & 63;
    int k0 = (t >> 6) * 4 + it * 16;
    unsigned short vv[4];
#pragma unroll
    for (int i = 0; i < 4; ++i) {
      int kk = k0 + i;
      unsigned short x = 0;
      if (kk < 32) {
        x = f2b(vc_ln[((size_t)(b * 32 + kk)) * 1024 + hoff + d]);
      } else if (kk < 104) {
        int pos = s0 - 4 + (kk - 32);
        if (pos >= 0 && pos < 4096)
          x = vbuf[((size_t)(b * 4096 + pos)) * 1024 + hoff + d];
      }
      vv[i] = x;
    }
    *(ushort4*)(Vt + d * 128 + (k0 ^ ((d & 31) << 2))) = *(ushort4*)vv;
  }
  __syncthreads();

  // ---- QK^T: wave w handles queries mbase..mbase+15 ----
  int mbase = w * 16;
  bf16x8 aq[2];
#pragma unroll
  for (int ks = 0; ks < 2; ++ks)
    aq[ks] = *(const bf16x8*)(Qs + (mbase + lr16) * 72 + ks * 32 + q4 * 8);
  f32x4 S[7];
#pragma unroll
  for (int nb = 0; nb < 7; ++nb) {
    f32x4 acc = {};
#pragma unroll
    for (int ks = 0; ks < 2; ++ks) {
      bf16x8 bk =
          *(const bf16x8*)(Ks + (nb * 16 + lr16) * 72 + ks * 32 + q4 * 8);
      acc = __builtin_amdgcn_mfma_f32_16x16x32_bf16(aq[ks], bk, acc, 0, 0, 0);
    }
    S[nb] = acc;
  }

  // ---- mask + softmax in-register ----
  float ex[7][4];
#pragma unroll
  for (int r = 0; r < 4; ++r) {
    int qrow = mbase + q4 * 4 + r;        // block-local query 0..63
    int g8 = (qrow >> 3) * 8;
    float m = -1e30f;
#pragma unroll
    for (int nb = 0; nb < 7; ++nb) {
      int col = nb * 16 + lr16;
      float v = S[nb][r];
      if (col >= 32) {
        int rw = col - 32;
        int pos = s0 - 4 + rw;
        bool ok = (rw >= g8) && (rw < g8 + 16) && (pos >= 0) && (pos < 4096);
        if (!ok) v = -INFINITY;
      }
      ex[nb][r] = v;
      m = fmaxf(m, v);
    }
    m = fmaxf(m, __shfl_xor(m, 1));
    m = fmaxf(m, __shfl_xor(m, 2));
    m = fmaxf(m, __shfl_xor(m, 4));
    m = fmaxf(m, __shfl_xor(m, 8));
    float s = 0.f;
#pragma unroll
    for (int nb = 0; nb < 7; ++nb) {
      float e = expf(ex[nb][r] - m);
      ex[nb][r] = e;
      s += e;
    }
    s += __shfl_xor(s, 1);
    s += __shfl_xor(s, 2);
    s += __shfl_xor(s, 4);
    s += __shfl_xor(s, 8);
    float inv = 1.0f / s;
#pragma unroll
    for (int nb = 0; nb < 7; ++nb) ex[nb][r] *= inv;
  }
  __syncthreads();   // all QK reads of Qs/Ks done; regionA now P/C

  // zero P pad cols 112..127 (swizzled blocks 14,15 per row)
  if (t < 128) {
    int q = t >> 1, blk = 14 + (t & 1);
    uint4 z = {0, 0, 0, 0};
    *(uint4*)(Ps + q * 128 + ((blk ^ (q & 7)) << 3)) = z;
  }
  // write P bf16 (swizzled 16B blocks)
#pragma unroll
  for (int r = 0; r < 4; ++r) {
    int q = mbase + q4 * 4 + r;
#pragma unroll
    for (int nb = 0; nb < 7; ++nb) {
      int col = nb * 16 + lr16;
      int blk = col >> 3;
      Ps[q * 128 + ((blk ^ (q & 7)) << 3) + (col & 7)] = f2b(ex[nb][r]);
    }
  }
  __syncthreads();

  // ---- PV: C[q][d] = sum_k P[q][k] * V[k][d] ----
  bf16x8 pa[4];
#pragma unroll
  for (int ks = 0; ks < 4; ++ks) {
    int q = mbase + lr16;
    int blk = ks * 4 + q4;
    pa[ks] = *(const bf16x8*)(Ps + q * 128 + ((blk ^ (q & 7)) << 3));
  }
#pragma unroll
  for (int nb = 0; nb < 4; ++nb) {
    f32x4 acc = {};
    int d = nb * 16 + lr16;
#pragma unroll
    for (int ks = 0; ks < 4; ++ks) {
      unsigned short vv[8];
#pragma unroll
      for (int jh = 0; jh < 2; ++jh) {
        int k4 = ks * 32 + q4 * 8 + jh * 4;
        *(ushort4*)(vv + jh * 4) =
            *(const ushort4*)(Vt + d * 128 + (k4 ^ ((d & 31) << 2)));
      }
      acc = __builtin_amdgcn_mfma_f32_16x16x32_bf16(pa[ks], *(const bf16x8*)vv,
                                                    acc, 0, 0, 0);
    }
#pragma unroll
    for (int r = 0; r < 4; ++r) {
      int row = mbase + q4 * 4 + r;
      Cs[row * 68 + d] = f2b(acc[r]);
    }
  }
  __syncthreads();

  // ---- store C (coalesced 16B) ----
#pragma unroll
  for (int it = 0; it < 2; ++it) {
    int sid = it * 256 + t;
    int row = sid >> 3, seg = sid & 7;
    ushort4 a0 = *(const ushort4*)(Cs + row * 68 + seg * 8);
    ushort4 a1 = *(const ushort4*)(Cs + row * 68 + seg * 8 + 4);
    unsigned short u[8];
    *(ushort4*)u = a0;
    *(ushort4*)(u + 4) = a1;
    *(uint4*)(qc + ((size_t)(b * 4096 + s0 + row)) * 1024 + hoff + seg * 8) =
        *(uint4*)u;
  }
}

// ---------------------------------------------------------------------------
extern "C" void kernel_launch(void* const* d_in, const int* in_sizes, int n_in,
                              void* d_out, int out_size, void* d_ws,
                              size_t ws_size, hipStream_t stream) {
  const float* query = (const float*)d_in[0];
  const float* Wq = (const float*)d_in[1];
  const float* bq = (const float*)d_in[2];
  const float* Wk = (const float*)d_in[3];
  const float* bk = (const float*)d_in[4];
  const float* Wv = (const float*)d_in[5];
  const float* bv = (const float*)d_in[6];
  const float* Wo = (const float*)d_in[7];
  const float* bo = (const float*)d_in[8];
  const float* g_l = (const float*)d_in[9];
  const float* b_l = (const float*)d_in[10];
  const float* g_s = (const float*)d_in[11];
  const float* b_s = (const float*)d_in[12];
  const float* Wd = (const float*)d_in[13];
  const float* bd = (const float*)d_in[14];
  float* out = (float*)d_out;

  // allow >64KB dynamic LDS for gemm128 (once per process)
  static bool attr_set = []() {
    hipFuncSetAttribute((const void*)gemm128,
                        hipFuncAttributeMaxDynamicSharedMemorySize, 73728);
    return true;
  }();
  (void)attr_set;

  // Workspace layout (~205 MB)
  unsigned short* qb = (unsigned short*)d_ws;  // 16,777,216 bf16 (Q, then C)
  unsigned short* kb = qb + 16777216;          // 16,777,216 bf16
  unsigned short* vb = kb + 16777216;          // 16,777,216 bf16
  unsigned short* xb = vb + 16777216;          // 16,777,216 bf16 (X)
  float* yd = (float*)(xb + 16777216);         // 8,388,608 fp32
  float* stats = yd + 8388608;                 // 4,096
  float* col_pm = stats + 4096;                // 32,768
  float* col_ps = col_pm + 32768;              // 32,768
  float* kc_part = col_ps + 32768;             // 4,194,304 (32 chunks)
  float* vc_part = kc_part + 4194304;          // 4,194,304
  float* kc_ln = vc_part + 4194304;            // 131,072
  float* vc_ln = kc_ln + 131072;               // 131,072
  // wAll: concatenated [WqT|WkT|WvT|WdT] rows (1024+1024+1024+512 = 3584)
  unsigned short* wAll = (unsigned short*)(vc_ln + 131072);  // 3,670,016
  unsigned short* woT = wAll + 3670016;        // 1,048,576

  dim3 blk(256);
  // bf16 conversions
  conv_rows<<<16384, blk, 0, stream>>>(query, xb);
  conv_wT_all<<<dim3(32, 32, 5), blk, 0, stream>>>(Wq, Wk, Wv, Wd, Wo,
                                                   wAll, woT);
  // Fused QKVD projections: 256x128 tiles, 1792 blocks, 2 blocks/CU
  gemm128<<<1792, dim3(512), 73728, stream>>>(xb, wAll, bq, bk, bv, bd,
                                              qb, kb, vb, yd, nullptr, 0);
  // LN K and V in one dispatch (kb,vb contiguous)
  ln_bf<<<32768, blk, 0, stream>>>(kb, g_l, b_l);
  // head-score softmax stats (two-phase, 512-block parallel)
  col_part<<<dim3(8, 4, 16), blk, 0, stream>>>(yd, col_pm, col_ps);
  col_combine<<<8, blk, 0, stream>>>(col_pm, col_ps, stats);
  // landmark compression + LN
  compress<<<dim3(NCHUNK, 16, 4), blk, 0, stream>>>(yd, stats, kb, vb,
                                                    kc_part, vc_part);
  ln_compress<<<dim3(128, 2), blk, 0, stream>>>(kc_part, vc_part, g_s, b_s,
                                                kc_ln, vc_ln);
  // fused attention (bf16 C overwrites qb)
  attention<<<dim3(64, 16, 4), blk, 0, stream>>>(qb, kb, vb, kc_ln, vc_ln);
  // output projection (+ (b,s)->(s,b) remap), reads bf16 C directly
  gemm128<<<512, dim3(512), 73728, stream>>>(qb, woT, bo, nullptr, nullptr,
                                             nullptr, nullptr, nullptr,
                                             nullptr, nullptr, out, 1);
}